// Round 1
// baseline (588.890 us; speedup 1.0000x reference)
//
#include <hip/hip_runtime.h>
#include <hip/hip_bf16.h>
#include <math.h>

typedef __hip_bfloat16 bf16;
typedef short short8 __attribute__((ext_vector_type(8)));
typedef short short4v __attribute__((ext_vector_type(4)));
typedef float floatx4 __attribute__((ext_vector_type(4)));

constexpr int CB_ = 32;
constexpr int CT = 256;
constexpr int CF = 512;
constexpr int CN = 508;
constexpr int CM = 4;
constexpr int CT2 = 512;
constexpr int MROWS = CB_ * CF;  // 16384
constexpr int PADL = 528;

__device__ __forceinline__ float b2f(bf16 v) { return __bfloat162float(v); }
__device__ __forceinline__ bf16 f2b(float v) { return __float2bfloat16(v); }
__device__ __forceinline__ float s2f(short s) {
    unsigned u = ((unsigned)(unsigned short)s) << 16;
    return __builtin_bit_cast(float, u);
}
__device__ __forceinline__ short f2s(float v) {
    bf16 t = __float2bfloat16(v);
    return __builtin_bit_cast(short, t);
}
__device__ __forceinline__ float silu_f(float x) { return x / (1.0f + __expf(-x)); }
__device__ __forceinline__ float softplus_f(float x) {
    return fmaxf(x, 0.0f) + __logf(1.0f + __expf(-fabsf(x)));
}

__device__ __forceinline__ void gl_lds16(const bf16* g, short* l) {
    __builtin_amdgcn_global_load_lds(
        (const __attribute__((address_space(1))) unsigned int*)(g),
        (__attribute__((address_space(3))) unsigned int*)(l), 16, 0, 0);
}

// ---- ALL prepack in one kernel: 8 weight transposes (+nw folding for inp/D),
// conv weight pack, xpT pad rows, CBv zero, plain-bf16 convlin copy (for the
// composite-weight GEMM), and composite cb biases bcb = convlin_b@fcW + fcb.
// fc2/fc3 interleaved: dst row = 2c (fc2) / 2c+1 (fc3). inp/D get nw_i folded
// into their K-rows so rmsnorm scale can be applied per-row in the GEMM epilogue.
constexpr int CONVN = 3 * 3 * 512 * 512;  // 2359296
constexpr int MTILES = 3520;
struct P8 { const float* s[8]; bf16* d[8]; };
__global__ __launch_bounds__(256) void prepack_all_kernel(P8 p, const float* __restrict__ nw,
                                                          const float* __restrict__ convW,
                                                          bf16* __restrict__ convD,
                                                          bf16* __restrict__ xpT,
                                                          float* __restrict__ CBv,
                                                          const float* __restrict__ clW,
                                                          bf16* __restrict__ clPlain,
                                                          const float* __restrict__ clb,
                                                          const float* __restrict__ pf2W,
                                                          const float* __restrict__ pf2b,
                                                          const float* __restrict__ pf3W,
                                                          const float* __restrict__ pf3b,
                                                          float* __restrict__ bcb) {
    int bid = blockIdx.x;
    if (bid >= MTILES) {
        int idx = (bid - MTILES) * 256 + threadIdx.x;
        if (idx < CONVN) {
            int ci = idx & 511;
            int co = (idx >> 9) & 511;
            int it = idx >> 18;
            int tap = it % 3, ib = it / 3;
            convD[idx] = f2b(convW[(((size_t)(ib * 512 + co)) * 512 + ci) * 3 + tap]);
        } else if (idx < CONVN + 32768) {
            int j = idx - CONVN;
            int ci = j & 511;
            int w = (j >> 9) & 1;
            int b = j >> 10;
            xpT[((size_t)b * PADL + (w ? 513 : 0)) * 512 + ci] = f2b(0.0f);
        } else if (idx < CONVN + 32768 + MROWS) {
            CBv[idx - CONVN - 32768] = 0.0f;
        } else if (idx < CONVN + 49152 + 786432) {
            // plain bf16 copy of convlin_W [3][512(in)][512(out)] (layout identical)
            int j = idx - CONVN - 49152;
            clPlain[j] = f2b(clW[j]);
        } else if (idx < CONVN + 49152 + 786432 + 1536) {
            // composite cb biases: bcb[z][2c+half] = sum_k convlin_b[z][k]*fcW[z][k][c] + fcb[z][c]
            int t = idx - CONVN - 49152 - 786432;
            int z = t >> 9, r = t & 511, c = r & 255, half = r >> 8;
            const float* fw = (half ? pf3W : pf2W) + (size_t)z * 131072;
            const float* cbp = clb + z * 512;
            float s = (half ? pf3b : pf2b)[z * 256 + c];
            for (int k = 0; k < 512; k++) s += cbp[k] * fw[k * 256 + c];
            bcb[z * 512 + 2 * c + half] = s;
        }
        return;
    }
    const int Ks[8]   = {256, 256, 512, 512, 512, 512, 512, 256};
    const int Ns[8]   = {512, 512, 512, 256, 256, 512, 256, 256};
    const int zs[8]   = {3, 3, 3, 3, 3, 3, 3, 1};
    const int dstr[8] = {262144, 262144, 524288, 524288, 524288, 524288, 131072, 65536};
    const int rml[8]  = {1, 1, 1, 2, 2, 1, 1, 1};
    const int rad[8]  = {0, 0, 0, 0, 1, 0, 0, 0};
    int m = 0, acc = 0;
    for (m = 0; m < 8; m++) {
        int c = (Ns[m] >> 5) * (Ks[m] >> 5) * zs[m];
        if (bid < acc + c) break;
        acc += c;
    }
    int lid = bid - acc;
    int K = Ks[m], N = Ns[m];
    int tx = N >> 5, ty = K >> 5;
    int z = lid / (tx * ty), rem = lid % (tx * ty);
    int k0 = (rem / tx) * 32, n0 = (rem % tx) * 32;
    const float* s = p.s[m] + (size_t)z * K * N;
    bf16* d = p.d[m] + (size_t)z * dstr[m];
    int mul = rml[m], add = rad[m];
    bool fold = (m <= 1);  // inp_W, D_W: fold nw_z into K-rows
    __shared__ float Ts[32][33];
    for (int e = threadIdx.x; e < 1024; e += 256) {
        int r = e >> 5, c = e & 31;
        float v = s[(size_t)(k0 + r) * N + n0 + c];
        if (fold) v *= nw[z * 256 + k0 + r];
        Ts[r][c] = v;
    }
    __syncthreads();
    for (int e = threadIdx.x; e < 1024; e += 256) {
        int r = e >> 5, c = e & 31;
        d[(size_t)((n0 + r) * mul + add) * K + k0 + c] = f2b(Ts[c][r]);
    }
}

// ---- composite weight GEMM: Wt23'[z][j][i] = sum_k fc23T[z][j][k] * convlin_plain[z][i][k]
// (i.e. (convlinW @ fc2W)^T / fc3 interleaved). Runs once at startup, 0.8 GF.
__global__ __launch_bounds__(256) void compw_kernel(const bf16* __restrict__ Asrc,
                                                    const bf16* __restrict__ Psrc,
                                                    bf16* __restrict__ Dst) {
    __shared__ __align__(16) short As[128 * 32];
    __shared__ __align__(16) short Bs[128 * 32];
    const int tid = threadIdx.x;
    const int lane = tid & 63;
    const int wave = tid >> 6;
    const int m0 = blockIdx.x * 128, n0 = blockIdx.y * 128;
    const int z = blockIdx.z;
    const bf16* A = Asrc + (size_t)z * 524288;
    const bf16* Wt = Psrc + (size_t)z * 262144;
    bf16* o = Dst + (size_t)z * 524288;

    const int srow0 = wave * 32;
    const int lrow = lane >> 2;
    const int lcol = (lane & 3) * 8;
    const bf16* aP0 = A + (size_t)(m0 + srow0 + lrow) * 512 + lcol;
    const bf16* aP1 = A + (size_t)(m0 + srow0 + 16 + lrow) * 512 + lcol;
    const bf16* bP0 = Wt + (size_t)(n0 + srow0 + lrow) * 512 + lcol;
    const bf16* bP1 = Wt + (size_t)(n0 + srow0 + 16 + lrow) * 512 + lcol;
    short* aL0 = &As[srow0 * 32];
    short* aL1 = &As[(srow0 + 16) * 32];
    short* bL0 = &Bs[srow0 * 32];
    short* bL1 = &Bs[(srow0 + 16) * 32];

    const int wm = (wave & 1) * 64, wn = (wave >> 1) * 64;
    const int fr = lane & 15, quad = lane >> 4;

    floatx4 acc[4][4];
    #pragma unroll
    for (int i = 0; i < 4; i++)
        #pragma unroll
        for (int j = 0; j < 4; j++) acc[i][j] = (floatx4){0.f, 0.f, 0.f, 0.f};

    for (int k0 = 0; k0 < 512; k0 += 32) {
        gl_lds16(aP0 + k0, aL0);
        gl_lds16(aP1 + k0, aL1);
        gl_lds16(bP0 + k0, bL0);
        gl_lds16(bP1 + k0, bL1);
        __syncthreads();
        short8 af[4], bfv[4];
        #pragma unroll
        for (int i = 0; i < 4; i++) af[i] = *(const short8*)&As[(wm + i * 16 + fr) * 32 + quad * 8];
        #pragma unroll
        for (int j = 0; j < 4; j++) bfv[j] = *(const short8*)&Bs[(wn + j * 16 + fr) * 32 + quad * 8];
        #pragma unroll
        for (int i = 0; i < 4; i++)
            #pragma unroll
            for (int j = 0; j < 4; j++)
                acc[i][j] = __builtin_amdgcn_mfma_f32_16x16x32_bf16(af[i], bfv[j], acc[i][j], 0, 0, 0);
        __syncthreads();
    }
    #pragma unroll
    for (int j = 0; j < 4; j++) {
        int n = n0 + wn + j * 16 + fr;
        #pragma unroll
        for (int i = 0; i < 4; i++) {
            int mb = m0 + wm + i * 16 + quad * 4;
            #pragma unroll
            for (int r = 0; r < 4; r++)
                o[(size_t)(mb + r) * 512 + n] = f2b(acc[i][j][r]);
        }
    }
}

// ---- fused stats + build_x (iter 0): writes RAW x (bf16) + rms scale SCL ----
__global__ __launch_bounds__(256) void buildx_kernel(
    const float* __restrict__ xe, const float* __restrict__ xm,
    float* __restrict__ means, float* __restrict__ stdev,
    bf16* __restrict__ X0, float* __restrict__ SCL) {
    __shared__ float L[256][65];
    __shared__ float red_s[4][64], red_q[4][64];
    __shared__ float stat_m[64], stat_i[64];
    int blk = blockIdx.x;
    int b = blk >> 3, f0 = (blk & 7) * 64;
    int tid = threadIdx.x;
    int j = tid & 63, tq = tid >> 6;
    int f = f0 + j;
    float ps = 0.f, pq = 0.f;
    const float* xep = xe + (size_t)b * CT * CN + f;
    const float* xmp = xm + (size_t)b * CT * CM + (f - CN);
    #pragma unroll 4
    for (int tt = 0; tt < 64; tt++) {
        int t = tq * 64 + tt;
        float v = (f < CN) ? xep[(size_t)t * CN] : xmp[(size_t)t * CM];
        L[t][j] = v;
        ps += v;
        pq += v * v;
    }
    red_s[tq][j] = ps;
    red_q[tq][j] = pq;
    __syncthreads();
    if (tid < 64) {
        int ff = f0 + tid;
        float s = red_s[0][tid] + red_s[1][tid] + red_s[2][tid] + red_s[3][tid];
        float q = red_q[0][tid] + red_q[1][tid] + red_q[2][tid] + red_q[3][tid];
        float mean, isd, msq;
        if (ff < CN) {
            mean = s * (1.0f / 256.0f);
            float var = fmaxf(q * (1.0f / 256.0f) - mean * mean, 0.0f);
            float sd = sqrtf(var + 1e-5f);
            isd = 1.0f / sd;
            means[b * CN + ff] = mean;
            stdev[b * CN + ff] = sd;
            msq = var / (var + 1e-5f);
        } else {
            mean = 0.0f;
            isd = 1.0f;
            msq = q * (1.0f / 256.0f);
        }
        stat_m[tid] = mean;
        stat_i[tid] = isd;
        SCL[b * 512 + ff] = rsqrtf(msq + 1e-5f);
    }
    __syncthreads();
    bf16* outp = X0 + ((size_t)(b * 512 + f0)) * 256;
    int t = tid;
    #pragma unroll 4
    for (int fp = 0; fp < 64; fp++) {
        float val = (L[t][fp] - stat_m[fp]) * stat_i[fp];
        outp[(size_t)fp * 256 + t] = f2b(val);
    }
}

// ---- MFMA GEMM (m97 structure). MODE 0: plain.
// MODE 1: [inp|D] with per-row SCL applied in epilogue (nw pre-folded into W).
// MODE 2: [convlin | fc2'⊕fc3' composite]: cols<512 plain XCO store (bias b1),
//         cols>=512 cb pair-product reduce (bias b2=bcb interleaved) + atomicAdd
//         into SCL (=CBv). ----
template <int MODE>
__global__ __launch_bounds__(256) void mgemm_kernel(const bf16* __restrict__ A,
                                                    const bf16* __restrict__ Wt,
                                                    const float* __restrict__ b1,
                                                    const float* __restrict__ b2,
                                                    float* __restrict__ SCL,
                                                    bf16* __restrict__ o1,
                                                    bf16* __restrict__ o2,
                                                    int K, int Ncols) {
    __shared__ __align__(16) short As[128 * 32];
    __shared__ __align__(16) short Bs[128 * 32];
    const int tid = threadIdx.x;
    const int lane = tid & 63;
    const int wave = tid >> 6;
    const int m0 = blockIdx.x * 128, n0 = blockIdx.y * 128;

    const int srow0 = wave * 32;
    const int lrow = lane >> 2;
    const int lcol = (lane & 3) * 8;

    const bf16* aP0 = A + (size_t)(m0 + srow0 + lrow) * K + lcol;
    const bf16* aP1 = A + (size_t)(m0 + srow0 + 16 + lrow) * K + lcol;
    const bf16* bP0 = Wt + (size_t)(n0 + srow0 + lrow) * K + lcol;
    const bf16* bP1 = Wt + (size_t)(n0 + srow0 + 16 + lrow) * K + lcol;
    short* aL0 = &As[srow0 * 32];
    short* aL1 = &As[(srow0 + 16) * 32];
    short* bL0 = &Bs[srow0 * 32];
    short* bL1 = &Bs[(srow0 + 16) * 32];

    const int wm = (wave & 1) * 64, wn = (wave >> 1) * 64;
    const int fr = lane & 15, quad = lane >> 4;

    floatx4 acc[4][4];
    #pragma unroll
    for (int i = 0; i < 4; i++)
        #pragma unroll
        for (int j = 0; j < 4; j++) acc[i][j] = (floatx4){0.f, 0.f, 0.f, 0.f};

    for (int k0 = 0; k0 < K; k0 += 32) {
        gl_lds16(aP0 + k0, aL0);
        gl_lds16(aP1 + k0, aL1);
        gl_lds16(bP0 + k0, bL0);
        gl_lds16(bP1 + k0, bL1);
        __syncthreads();
        short8 af[4], bfv[4];
        #pragma unroll
        for (int i = 0; i < 4; i++) af[i] = *(const short8*)&As[(wm + i * 16 + fr) * 32 + quad * 8];
        #pragma unroll
        for (int j = 0; j < 4; j++) bfv[j] = *(const short8*)&Bs[(wn + j * 16 + fr) * 32 + quad * 8];
        #pragma unroll
        for (int i = 0; i < 4; i++)
            #pragma unroll
            for (int j = 0; j < 4; j++)
                acc[i][j] = __builtin_amdgcn_mfma_f32_16x16x32_bf16(af[i], bfv[j], acc[i][j], 0, 0, 0);
        __syncthreads();
    }

    if (MODE == 0 || (MODE == 2 && n0 + wn < 512)) {
        #pragma unroll
        for (int j = 0; j < 4; j++) {
            int n = n0 + wn + j * 16 + fr;
            float bv = b1[n];
            #pragma unroll
            for (int i = 0; i < 4; i++) {
                int mb = m0 + wm + i * 16 + quad * 4;
                #pragma unroll
                for (int r = 0; r < 4; r++)
                    o1[(size_t)(mb + r) * Ncols + n] = f2b(acc[i][j][r] + bv);
            }
        }
    } else if (MODE == 2) {  // cb pair-product reduce into CBv (=SCL param)
        int nnb = n0 + wn - 512;
        float bv[4];
        #pragma unroll
        for (int j = 0; j < 4; j++) bv[j] = b2[nnb + j * 16 + fr];
        #pragma unroll
        for (int i = 0; i < 4; i++) {
            #pragma unroll
            for (int r = 0; r < 4; r++) {
                float s = 0.f;
                #pragma unroll
                for (int j = 0; j < 4; j++) {
                    float v = acc[i][j][r] + bv[j];
                    s += v * __shfl_xor(v, 1);
                }
                s += __shfl_xor(s, 2);
                s += __shfl_xor(s, 4);
                s += __shfl_xor(s, 8);
                if (fr == 0)
                    atomicAdd(&SCL[m0 + wm + i * 16 + quad * 4 + r], s * 0.5f);
            }
        }
    } else {  // MODE 1: [inp|D] with per-row rms scale
        if (n0 + wn < 512) {
            int b = (m0 + wm) >> 9;
            #pragma unroll
            for (int i = 0; i < 4; i++) {
                int mb = m0 + wm + i * 16 + quad * 4;
                float sclr[4];
                #pragma unroll
                for (int r = 0; r < 4; r++) sclr[r] = SCL[mb + r];
                #pragma unroll
                for (int j = 0; j < 4; j++) {
                    int n = n0 + wn + j * 16 + fr;
                    float bv = b1[n];
                    bf16* dst = o1 + ((size_t)b * PADL + n + 1) * 512;
                    int ci = mb & 511;
                    short4v pk;
                    #pragma unroll
                    for (int r = 0; r < 4; r++) pk[r] = f2s(acc[i][j][r] * sclr[r] + bv);
                    *(short4v*)(dst + ci) = pk;
                }
            }
        } else {
            #pragma unroll
            for (int i = 0; i < 4; i++) {
                int mb = m0 + wm + i * 16 + quad * 4;
                float sclr[4];
                #pragma unroll
                for (int r = 0; r < 4; r++) sclr[r] = SCL[mb + r];
                #pragma unroll
                for (int j = 0; j < 4; j++) {
                    int n = n0 + wn + j * 16 + fr;
                    float bv = b2[n - 512];
                    #pragma unroll
                    for (int r = 0; r < 4; r++)
                        o2[(size_t)(mb + r) * 512 + (n - 512)] =
                            f2b(silu_f(acc[i][j][r] * sclr[r] + bv));
                }
            }
        }
    }
}

// ---- fc1 GEMM with FUSED s6 gate epilogue ----
__global__ __launch_bounds__(256) void fc1gate_kernel(const bf16* __restrict__ A,
                                                      const bf16* __restrict__ Wt,
                                                      const float* __restrict__ b1,
                                                      const float* __restrict__ CBv,
                                                      const bf16* __restrict__ Xres,
                                                      bf16* __restrict__ G) {
    __shared__ __align__(16) short As[128 * 32];
    __shared__ __align__(16) short Bs[128 * 32];
    const int tid = threadIdx.x;
    const int lane = tid & 63;
    const int wave = tid >> 6;
    const int m0 = blockIdx.x * 128, n0 = blockIdx.y * 128;

    const int srow0 = wave * 32;
    const int lrow = lane >> 2;
    const int lcol = (lane & 3) * 8;
    const bf16* aP0 = A + (size_t)(m0 + srow0 + lrow) * 512 + lcol;
    const bf16* aP1 = A + (size_t)(m0 + srow0 + 16 + lrow) * 512 + lcol;
    const bf16* bP0 = Wt + (size_t)(n0 + srow0 + lrow) * 512 + lcol;
    const bf16* bP1 = Wt + (size_t)(n0 + srow0 + 16 + lrow) * 512 + lcol;
    short* aL0 = &As[srow0 * 32];
    short* aL1 = &As[(srow0 + 16) * 32];
    short* bL0 = &Bs[srow0 * 32];
    short* bL1 = &Bs[(srow0 + 16) * 32];

    const int wm = (wave & 1) * 64, wn = (wave >> 1) * 64;
    const int fr = lane & 15, quad = lane >> 4;

    floatx4 acc[4][4];
    #pragma unroll
    for (int i = 0; i < 4; i++)
        #pragma unroll
        for (int j = 0; j < 4; j++) acc[i][j] = (floatx4){0.f, 0.f, 0.f, 0.f};

    for (int k0 = 0; k0 < 512; k0 += 32) {
        gl_lds16(aP0 + k0, aL0);
        gl_lds16(aP1 + k0, aL1);
        gl_lds16(bP0 + k0, bL0);
        gl_lds16(bP1 + k0, bL1);
        __syncthreads();
        short8 af[4], bfv[4];
        #pragma unroll
        for (int i = 0; i < 4; i++) af[i] = *(const short8*)&As[(wm + i * 16 + fr) * 32 + quad * 8];
        #pragma unroll
        for (int j = 0; j < 4; j++) bfv[j] = *(const short8*)&Bs[(wn + j * 16 + fr) * 32 + quad * 8];
        #pragma unroll
        for (int i = 0; i < 4; i++)
            #pragma unroll
            for (int j = 0; j < 4; j++)
                acc[i][j] = __builtin_amdgcn_mfma_f32_16x16x32_bf16(af[i], bfv[j], acc[i][j], 0, 0, 0);
        __syncthreads();
    }
    #pragma unroll
    for (int i = 0; i < 4; i++) {
        int mb = m0 + wm + i * 16 + quad * 4;
        float cbr[4];
        #pragma unroll
        for (int r = 0; r < 4; r++) cbr[r] = CBv[mb + r];
        #pragma unroll
        for (int j = 0; j < 4; j++) {
            int n = n0 + wn + j * 16 + fr;
            float bv = b1[n];
            #pragma unroll
            for (int r = 0; r < 4; r++) {
                size_t off = (size_t)(mb + r) * 512 + n;
                float delta = softplus_f(acc[i][j][r] + bv);
                float xssm = delta * b2f(A[off]) * cbr[r];
                G[off] = f2b(silu_f(xssm) * b2f(Xres[off]));
            }
        }
    }
}

// ---- conv as implicit MFMA GEMM + CBv zeroing at entry ----
__global__ __launch_bounds__(256) void conv_mfma_kernel(const bf16* __restrict__ Wc,
                                                        const bf16* __restrict__ xpT,
                                                        const float* __restrict__ bias,
                                                        bf16* __restrict__ Out,
                                                        float* __restrict__ CBvZ) {
    __shared__ __align__(16) short As[3 * 128 * 32];
    __shared__ __align__(16) short Bs[144 * 32];
    const int tid = threadIdx.x;
    const int lane = tid & 63;
    const int wave = tid >> 6;
    int bx = blockIdx.x;
    if (bx < 128 && tid < 128) CBvZ[bx * 128 + tid] = 0.0f;
    int xcd = bx & 7, g = bx >> 3;
    int mt = g & 3;
    int id = xcd * 16 + (g >> 2);
    int nt = id & 3, b = id >> 2;
    const int m0 = mt * 128, n0 = nt * 128;
    const bf16* xb = xpT + (size_t)b * PADL * 512;

    const int lrow = lane >> 2;
    const int lcol = (lane & 3) * 8;
    const int wm = (wave & 1) * 64, wn = (wave >> 1) * 64;
    const int fr = lane & 15, quad = lane >> 4;

    floatx4 acc[4][4];
    #pragma unroll
    for (int i = 0; i < 4; i++)
        #pragma unroll
        for (int j = 0; j < 4; j++) acc[i][j] = (floatx4){0.f, 0.f, 0.f, 0.f};

    for (int k0 = 0; k0 < 512; k0 += 32) {
        for (int ga = wave; ga < 24; ga += 4) {
            int tap = ga >> 3, rg = ga & 7;
            gl_lds16(Wc + (size_t)tap * 262144 + (size_t)(m0 + rg * 16 + lrow) * 512 + k0 + lcol,
                     &As[ga * 512]);
        }
        for (int gb = wave; gb < 9; gb += 4) {
            gl_lds16(xb + (size_t)(n0 + gb * 16 + lrow) * 512 + k0 + lcol, &Bs[gb * 512]);
        }
        __syncthreads();
        #pragma unroll
        for (int tap = 0; tap < 3; tap++) {
            short8 af[4], bfv[4];
            #pragma unroll
            for (int i = 0; i < 4; i++)
                af[i] = *(const short8*)&As[tap * 4096 + (wm + i * 16 + fr) * 32 + quad * 8];
            #pragma unroll
            for (int j = 0; j < 4; j++)
                bfv[j] = *(const short8*)&Bs[(wn + j * 16 + fr + tap) * 32 + quad * 8];
            #pragma unroll
            for (int i = 0; i < 4; i++)
                #pragma unroll
                for (int j = 0; j < 4; j++)
                    acc[i][j] = __builtin_amdgcn_mfma_f32_16x16x32_bf16(af[i], bfv[j], acc[i][j], 0, 0, 0);
        }
        __syncthreads();
    }
    bf16* ob = Out + (size_t)b * CF * CT2;
    #pragma unroll
    for (int i = 0; i < 4; i++) {
        int mb = m0 + wm + i * 16 + quad * 4;
        #pragma unroll
        for (int r = 0; r < 4; r++) {
            float bv = bias[mb + r];
            #pragma unroll
            for (int j = 0; j < 4; j++) {
                int n = n0 + wn + j * 16 + fr;
                ob[(size_t)(mb + r) * CT2 + n] = f2b(silu_f(acc[i][j][r] + bv));
            }
        }
    }
}

// ---- out-GEMM (K=512, N=256) + rms scale computation (NOT applied): writes
// x_next (bf16) + SCL[row] (fp32). nw application deferred to next GEMM (folded W).
__global__ __launch_bounds__(256) void gemm_scl_kernel(const bf16* __restrict__ A,
                                                       const bf16* __restrict__ Wt,
                                                       const float* __restrict__ bias,
                                                       bf16* __restrict__ Xo,
                                                       float* __restrict__ SCL) {
    __shared__ __align__(16) short As[64 * 32];
    __shared__ __align__(16) short Bs[256 * 32];
    __shared__ float red[4][64];
    const int tid = threadIdx.x;
    const int lane = tid & 63;
    const int wave = tid >> 6;
    const int m0 = blockIdx.x * 64;

    const int lrow = lane >> 2;
    const int lcol = (lane & 3) * 8;
    const bf16* aP = A + (size_t)(m0 + wave * 16 + lrow) * 512 + lcol;
    short* aL = &As[wave * 16 * 32];
    const bf16* bP[4];
    short* bL[4];
    #pragma unroll
    for (int g = 0; g < 4; g++) {
        int r0 = (wave * 4 + g) * 16;
        bP[g] = Wt + (size_t)(r0 + lrow) * 512 + lcol;
        bL[g] = &Bs[r0 * 32];
    }
    const int wn = wave * 64;
    const int fr = lane & 15, quad = lane >> 4;

    floatx4 acc[4][4];
    #pragma unroll
    for (int i = 0; i < 4; i++)
        #pragma unroll
        for (int j = 0; j < 4; j++) acc[i][j] = (floatx4){0.f, 0.f, 0.f, 0.f};

    for (int k0 = 0; k0 < 512; k0 += 32) {
        gl_lds16(aP + k0, aL);
        #pragma unroll
        for (int g = 0; g < 4; g++) gl_lds16(bP[g] + k0, bL[g]);
        __syncthreads();
        short8 af[4], bfv[4];
        #pragma unroll
        for (int i = 0; i < 4; i++) af[i] = *(const short8*)&As[(i * 16 + fr) * 32 + quad * 8];
        #pragma unroll
        for (int j = 0; j < 4; j++) bfv[j] = *(const short8*)&Bs[(wn + j * 16 + fr) * 32 + quad * 8];
        #pragma unroll
        for (int i = 0; i < 4; i++)
            #pragma unroll
            for (int j = 0; j < 4; j++)
                acc[i][j] = __builtin_amdgcn_mfma_f32_16x16x32_bf16(af[i], bfv[j], acc[i][j], 0, 0, 0);
        __syncthreads();
    }
    #pragma unroll
    for (int j = 0; j < 4; j++) {
        float bv = bias[wn + j * 16 + fr];
        #pragma unroll
        for (int i = 0; i < 4; i++)
            #pragma unroll
            for (int r = 0; r < 4; r++) acc[i][j][r] += bv;
    }
    #pragma unroll
    for (int i = 0; i < 4; i++) {
        #pragma unroll
        for (int r = 0; r < 4; r++) {
            float s = 0.f;
            #pragma unroll
            for (int j = 0; j < 4; j++) s += acc[i][j][r] * acc[i][j][r];
            #pragma unroll
            for (int o = 8; o > 0; o >>= 1) s += __shfl_xor(s, o);
            if (fr == 0) red[wave][i * 16 + quad * 4 + r] = s;
        }
    }
    __syncthreads();
    if (tid < 64) {
        float tot = red[0][tid] + red[1][tid] + red[2][tid] + red[3][tid];
        SCL[m0 + tid] = rsqrtf(tot * (1.0f / CT) + 1e-5f);
    }
    #pragma unroll
    for (int j = 0; j < 4; j++) {
        int n = wn + j * 16 + fr;
        #pragma unroll
        for (int i = 0; i < 4; i++) {
            int rl = i * 16 + quad * 4;
            #pragma unroll
            for (int r = 0; r < 4; r++)
                Xo[(size_t)(m0 + rl + r) * CT + n] = f2b(acc[i][j][r]);
        }
    }
}

// ---- proj GEMM (K=256, N=256) with fused de-norm + transpose to fp32 out ----
__global__ __launch_bounds__(256) void proj_out_kernel(const bf16* __restrict__ A,
                                                       const bf16* __restrict__ Wt,
                                                       const float* __restrict__ bias,
                                                       const float* __restrict__ means,
                                                       const float* __restrict__ stdev,
                                                       float* __restrict__ out) {
    __shared__ __align__(16) short As[128 * 32];
    __shared__ __align__(16) short Bs[128 * 32];
    const int tid = threadIdx.x;
    const int lane = tid & 63;
    const int wave = tid >> 6;
    const int m0 = blockIdx.x * 128, n0 = blockIdx.y * 128;

    const int srow0 = wave * 32;
    const int lrow = lane >> 2;
    const int lcol = (lane & 3) * 8;
    const bf16* aP0 = A + (size_t)(m0 + srow0 + lrow) * 256 + lcol;
    const bf16* aP1 = A + (size_t)(m0 + srow0 + 16 + lrow) * 256 + lcol;
    const bf16* bP0 = Wt + (size_t)(n0 + srow0 + lrow) * 256 + lcol;
    const bf16* bP1 = Wt + (size_t)(n0 + srow0 + 16 + lrow) * 256 + lcol;
    short* aL0 = &As[srow0 * 32];
    short* aL1 = &As[(srow0 + 16) * 32];
    short* bL0 = &Bs[srow0 * 32];
    short* bL1 = &Bs[(srow0 + 16) * 32];

    const int wm = (wave & 1) * 64, wn = (wave >> 1) * 64;
    const int fr = lane & 15, quad = lane >> 4;

    floatx4 acc[4][4];
    #pragma unroll
    for (int i = 0; i < 4; i++)
        #pragma unroll
        for (int j = 0; j < 4; j++) acc[i][j] = (floatx4){0.f, 0.f, 0.f, 0.f};

    for (int k0 = 0; k0 < 256; k0 += 32) {
        gl_lds16(aP0 + k0, aL0);
        gl_lds16(aP1 + k0, aL1);
        gl_lds16(bP0 + k0, bL0);
        gl_lds16(bP1 + k0, bL1);
        __syncthreads();
        short8 af[4], bfv[4];
        #pragma unroll
        for (int i = 0; i < 4; i++) af[i] = *(const short8*)&As[(wm + i * 16 + fr) * 32 + quad * 8];
        #pragma unroll
        for (int j = 0; j < 4; j++) bfv[j] = *(const short8*)&Bs[(wn + j * 16 + fr) * 32 + quad * 8];
        #pragma unroll
        for (int i = 0; i < 4; i++)
            #pragma unroll
            for (int j = 0; j < 4; j++)
                acc[i][j] = __builtin_amdgcn_mfma_f32_16x16x32_bf16(af[i], bfv[j], acc[i][j], 0, 0, 0);
        __syncthreads();
    }
    #pragma unroll
    for (int j = 0; j < 4; j++) {
        int t = n0 + wn + j * 16 + fr;
        float bv = bias[t];
        #pragma unroll
        for (int i = 0; i < 4; i++) {
            int mb = m0 + wm + i * 16 + quad * 4;
            int b = mb >> 9;
            int nv = mb & 511;
            if (nv < CN) {
                floatx4 o;
                #pragma unroll
                for (int r = 0; r < 4; r++) {
                    int sn = b * CN + nv + r;
                    o[r] = (acc[i][j][r] + bv) * stdev[sn] + means[sn];
                }
                *(floatx4*)(out + ((size_t)(b * CT + t)) * CN + nv) = o;
            }
        }
    }
}

extern "C" void kernel_launch(void* const* d_in, const int* in_sizes, int n_in,
                              void* d_out, int out_size, void* d_ws, size_t ws_size,
                              hipStream_t stream) {
    const float* x_enc  = (const float*)d_in[0];
    const float* x_mark = (const float*)d_in[1];
    const float* norm_w = (const float*)d_in[4];
    const float* inp_W  = (const float*)d_in[5];
    const float* inp_b  = (const float*)d_in[6];
    const float* conv_W = (const float*)d_in[7];
    const float* conv_b = (const float*)d_in[8];
    const float* convlin_W = (const float*)d_in[9];
    const float* convlin_b = (const float*)d_in[10];
    const float* fc1_W = (const float*)d_in[11];
    const float* fc1_b = (const float*)d_in[12];
    const float* fc2_W = (const float*)d_in[13];
    const float* fc2_b = (const float*)d_in[14];
    const float* fc3_W = (const float*)d_in[15];
    const float* fc3_b = (const float*)d_in[16];
    const float* D_W   = (const float*)d_in[17];
    const float* D_b   = (const float*)d_in[18];
    const float* out_W = (const float*)d_in[19];
    const float* out_b = (const float*)d_in[20];
    const float* proj_W = (const float*)d_in[21];
    const float* proj_b = (const float*)d_in[22];

    // ---- workspace layout ----
    char* ws = (char*)d_ws;
    float* MEANS = (float*)(ws);
    float* STDEV = (float*)(ws + 65536);
    float* CBv   = (float*)(ws + 131072);
    float* SCL   = (float*)(ws + 196608);    // 64 KB slot (16384 fp32)
    bf16* wb = (bf16*)(ws + 262144);
    bf16* wt_g1      = wb;                   // 3 x [1024][256]  (nw-folded inp^T | D^T)
    bf16* wt_g3      = wb + 786432;          // 3 x [fc1^T | fc2⊕fc3^T]
    bf16* wt_merged  = wb + 2359296;         // 3 x [1024][512]  (convlin^T | composite fc2'⊕fc3')
    bf16* wt_out     = wb + 3932160;         // 3 x [256][512]
    bf16* wt_proj    = wb + 4325376;         // [256][256]
    bf16* wt_conv    = wb + 4390912;         // 3 x [3][512][512]
    bf16* cl_plain   = wb + 6750208;         // 3 x [512][512] plain bf16 convlin
    float* bcb = (float*)(ws + 15335424);    // 3 x [512] interleaved composite cb biases
    bf16* xpT = (bf16*)(ws + 15728640);      // [32][528][512]
    const size_t POOLB = 16777216;
    bf16* pool[4] = {
        (bf16*)(ws + 33554432),
        (bf16*)(ws + 33554432 + POOLB),
        (bf16*)(ws + 33554432 + 2 * POOLB),
        (bf16*)(ws + 33554432 + 3 * POOLB),
    };
    float* out = (float*)d_out;

    // ---- single merged prepack (weights + conv + pads + CBv zero + composite biases) ----
    P8 p;
    p.s[0] = inp_W;  p.d[0] = wt_g1;
    p.s[1] = D_W;    p.d[1] = wt_g1 + 131072;
    p.s[2] = fc1_W;  p.d[2] = wt_g3;
    p.s[3] = fc2_W;  p.d[3] = wt_g3 + 262144;
    p.s[4] = fc3_W;  p.d[4] = wt_g3 + 262144;
    p.s[5] = convlin_W; p.d[5] = wt_merged;   // rows 0..511 per layer (stride 524288)
    p.s[6] = out_W;  p.d[6] = wt_out;
    p.s[7] = proj_W; p.d[7] = wt_proj;
    int tailN = CONVN + 49152 + 786432 + 1536;
    int convBlocks = (tailN + 255) / 256;
    prepack_all_kernel<<<MTILES + convBlocks, 256, 0, stream>>>(
        p, norm_w, conv_W, wt_conv, xpT, CBv,
        convlin_W, cl_plain, convlin_b, fc2_W, fc2_b, fc3_W, fc3_b, bcb);

    // ---- composite weights: (convlinW @ fc2W)^T / fc3 interleaved -> wt_merged rows 512.. ----
    compw_kernel<<<dim3(4, 4, 3), 256, 0, stream>>>(wt_g3 + 262144, cl_plain, wt_merged + 262144);

    // ---- stats + build: raw x -> pool[0].lo, rms scale -> SCL ----
    buildx_kernel<<<256, 256, 0, stream>>>(x_enc, x_mark, MEANS, STDEV, pool[0], SCL);

    // 4-pool rotation
    int ia = 0, ico = 1, ires = 2, iout = 3;
    for (int i = 0; i < 3; i++) {
        bf16* A  = pool[ia];
        bf16* XCO = pool[ico];
        bf16* XRES = pool[ires];
        bf16* OUTP = pool[iout];

        // [xp|xres] = (x*scl) @ [nw∘inp | nw∘D] + b : xp -> xpT^T, xres -> XRES
        mgemm_kernel<1><<<dim3(128, 8), 256, 0, stream>>>(
            A, wt_g1 + (size_t)i * 262144, inp_b + i * CT2, D_b + i * CT2, SCL,
            xpT, XRES, 256, 1024);
        // xc = silu(conv(xp)) -> A ; zeroes CBv
        conv_mfma_kernel<<<512, 256, 0, stream>>>(wt_conv + (size_t)i * 786432, xpT,
                                                  conv_b + i * CF, A, CBv);
        // merged: xco = xc @ convlin + b -> XCO   AND   cb atomics via composite fc2'/fc3'
        mgemm_kernel<2><<<dim3(128, 8), 256, 0, stream>>>(
            A, wt_merged + (size_t)i * 524288, convlin_b + i * CT2, bcb + i * 512, CBv,
            XCO, nullptr, 512, 512);
        // g = gate(fc1, xco, cb, xres) -> A
        fc1gate_kernel<<<dim3(128, 4), 256, 0, stream>>>(
            XCO, wt_g3 + (size_t)i * 524288, fc1_b + i * CT2, CBv, XRES, A);
        // x_next = g @ out_W + b -> OUTP.lo ; scl -> SCL
        gemm_scl_kernel<<<256, 256, 0, stream>>>(
            A, wt_out + (size_t)i * 131072, out_b + i * CT, OUTP, SCL);

        int na = iout, nco = ia, nres = ico, nout = ires;
        ia = na; ico = nco; ires = nres; iout = nout;
    }

    // x_final in pool[ia].lo. dec = x @ proj_W + b, de-norm + transpose to out
    proj_out_kernel<<<dim3(128, 2), 256, 0, stream>>>(
        pool[ia], wt_proj, proj_b, MEANS, STDEV, out);
}

// Round 2
// 568.486 us; speedup vs baseline: 1.0359x; 1.0359x over previous
//
#include <hip/hip_runtime.h>
#include <hip/hip_bf16.h>
#include <math.h>

typedef __hip_bfloat16 bf16;
typedef short short8 __attribute__((ext_vector_type(8)));
typedef short short4v __attribute__((ext_vector_type(4)));
typedef float floatx4 __attribute__((ext_vector_type(4)));

constexpr int CB_ = 32;
constexpr int CT = 256;
constexpr int CF = 512;
constexpr int CN = 508;
constexpr int CM = 4;
constexpr int CT2 = 512;
constexpr int MROWS = CB_ * CF;  // 16384
constexpr int PADL = 528;

__device__ __forceinline__ float b2f(bf16 v) { return __bfloat162float(v); }
__device__ __forceinline__ bf16 f2b(float v) { return __float2bfloat16(v); }
__device__ __forceinline__ short f2s(float v) {
    bf16 t = __float2bfloat16(v);
    return __builtin_bit_cast(short, t);
}
__device__ __forceinline__ float silu_f(float x) { return x / (1.0f + __expf(-x)); }
__device__ __forceinline__ float softplus_f(float x) {
    return fmaxf(x, 0.0f) + __logf(1.0f + __expf(-fabsf(x)));
}

__device__ __forceinline__ void gl_lds16(const bf16* g, short* l) {
    __builtin_amdgcn_global_load_lds(
        (const __attribute__((address_space(1))) unsigned int*)(g),
        (__attribute__((address_space(3))) unsigned int*)(l), 16, 0, 0);
}

// BK=64 LDS tiles: [rows][64 shorts] (128B rows). gl_lds16 covers 8 rows x 64 cols.
// XOR swizzle: LDS slot (row, col16) holds global (row, col16 ^ (row&7)).
// Source addr per lane: row += lane>>3 ; col16 = (lane&7) ^ (lane>>3).
// ds_read col16' = (s*4+quad) ^ (row&7) recovers k = s*32 + quad*8.

// ---- ALL prepack in one kernel: 8 weight transposes (+nw folding for inp/D),
// conv weight pack, xpT pad rows, CBv zero.
constexpr int CONVN = 3 * 3 * 512 * 512;  // 2359296
constexpr int MTILES = 3520;
struct P8 { const float* s[8]; bf16* d[8]; };
__global__ __launch_bounds__(256) void prepack_all_kernel(P8 p, const float* __restrict__ nw,
                                                          const float* __restrict__ convW,
                                                          bf16* __restrict__ convD,
                                                          bf16* __restrict__ xpT,
                                                          float* __restrict__ CBv) {
    int bid = blockIdx.x;
    if (bid >= MTILES) {
        int idx = (bid - MTILES) * 256 + threadIdx.x;
        if (idx < CONVN) {
            int ci = idx & 511;
            int co = (idx >> 9) & 511;
            int it = idx >> 18;
            int tap = it % 3, ib = it / 3;
            convD[idx] = f2b(convW[(((size_t)(ib * 512 + co)) * 512 + ci) * 3 + tap]);
        } else if (idx < CONVN + 32768) {
            int j = idx - CONVN;
            int ci = j & 511;
            int w = (j >> 9) & 1;
            int b = j >> 10;
            xpT[((size_t)b * PADL + (w ? 513 : 0)) * 512 + ci] = f2b(0.0f);
        } else if (idx < CONVN + 32768 + MROWS) {
            CBv[idx - CONVN - 32768] = 0.0f;
        }
        return;
    }
    const int Ks[8]   = {256, 256, 512, 512, 512, 512, 512, 256};
    const int Ns[8]   = {512, 512, 512, 256, 256, 512, 256, 256};
    const int zs[8]   = {3, 3, 3, 3, 3, 3, 3, 1};
    const int dstr[8] = {262144, 262144, 524288, 524288, 524288, 262144, 131072, 65536};
    const int rml[8]  = {1, 1, 1, 2, 2, 1, 1, 1};
    const int rad[8]  = {0, 0, 0, 0, 1, 0, 0, 0};
    int m = 0, acc = 0;
    for (m = 0; m < 8; m++) {
        int c = (Ns[m] >> 5) * (Ks[m] >> 5) * zs[m];
        if (bid < acc + c) break;
        acc += c;
    }
    int lid = bid - acc;
    int K = Ks[m], N = Ns[m];
    int tx = N >> 5, ty = K >> 5;
    int z = lid / (tx * ty), rem = lid % (tx * ty);
    int k0 = (rem / tx) * 32, n0 = (rem % tx) * 32;
    const float* s = p.s[m] + (size_t)z * K * N;
    bf16* d = p.d[m] + (size_t)z * dstr[m];
    int mul = rml[m], add = rad[m];
    bool fold = (m <= 1);  // inp_W, D_W: fold nw_z into K-rows
    __shared__ float Ts[32][33];
    for (int e = threadIdx.x; e < 1024; e += 256) {
        int r = e >> 5, c = e & 31;
        float v = s[(size_t)(k0 + r) * N + n0 + c];
        if (fold) v *= nw[z * 256 + k0 + r];
        Ts[r][c] = v;
    }
    __syncthreads();
    for (int e = threadIdx.x; e < 1024; e += 256) {
        int r = e >> 5, c = e & 31;
        d[(size_t)((n0 + r) * mul + add) * K + k0 + c] = f2b(Ts[c][r]);
    }
}

// ---- fused stats + build_x (iter 0): writes RAW x (bf16) + rms scale SCL ----
__global__ __launch_bounds__(256) void buildx_kernel(
    const float* __restrict__ xe, const float* __restrict__ xm,
    float* __restrict__ means, float* __restrict__ stdev,
    bf16* __restrict__ X0, float* __restrict__ SCL) {
    __shared__ float L[256][65];
    __shared__ float red_s[4][64], red_q[4][64];
    __shared__ float stat_m[64], stat_i[64];
    int blk = blockIdx.x;
    int b = blk >> 3, f0 = (blk & 7) * 64;
    int tid = threadIdx.x;
    int j = tid & 63, tq = tid >> 6;
    int f = f0 + j;
    float ps = 0.f, pq = 0.f;
    const float* xep = xe + (size_t)b * CT * CN + f;
    const float* xmp = xm + (size_t)b * CT * CM + (f - CN);
    #pragma unroll 4
    for (int tt = 0; tt < 64; tt++) {
        int t = tq * 64 + tt;
        float v = (f < CN) ? xep[(size_t)t * CN] : xmp[(size_t)t * CM];
        L[t][j] = v;
        ps += v;
        pq += v * v;
    }
    red_s[tq][j] = ps;
    red_q[tq][j] = pq;
    __syncthreads();
    if (tid < 64) {
        int ff = f0 + tid;
        float s = red_s[0][tid] + red_s[1][tid] + red_s[2][tid] + red_s[3][tid];
        float q = red_q[0][tid] + red_q[1][tid] + red_q[2][tid] + red_q[3][tid];
        float mean, isd, msq;
        if (ff < CN) {
            mean = s * (1.0f / 256.0f);
            float var = fmaxf(q * (1.0f / 256.0f) - mean * mean, 0.0f);
            float sd = sqrtf(var + 1e-5f);
            isd = 1.0f / sd;
            means[b * CN + ff] = mean;
            stdev[b * CN + ff] = sd;
            msq = var / (var + 1e-5f);
        } else {
            mean = 0.0f;
            isd = 1.0f;
            msq = q * (1.0f / 256.0f);
        }
        stat_m[tid] = mean;
        stat_i[tid] = isd;
        SCL[b * 512 + ff] = rsqrtf(msq + 1e-5f);
    }
    __syncthreads();
    bf16* outp = X0 + ((size_t)(b * 512 + f0)) * 256;
    int t = tid;
    #pragma unroll 4
    for (int fp = 0; fp < 64; fp++) {
        float val = (L[t][fp] - stat_m[fp]) * stat_i[fp];
        outp[(size_t)fp * 256 + t] = f2b(val);
    }
}

// ---- MFMA GEMM, BK=64 double-K-step (half the barriers). MODE 0: plain.
// MODE 1: [inp|D] with per-row SCL applied in epilogue (nw pre-folded into W). ----
template <int MODE>
__global__ __launch_bounds__(256) void mgemm_kernel(const bf16* __restrict__ A,
                                                    const bf16* __restrict__ Wt,
                                                    const float* __restrict__ b1,
                                                    const float* __restrict__ b2,
                                                    const float* __restrict__ SCL,
                                                    bf16* __restrict__ o1,
                                                    bf16* __restrict__ o2,
                                                    int K, int Ncols) {
    __shared__ __align__(16) short As[128 * 64];
    __shared__ __align__(16) short Bs[128 * 64];
    const int tid = threadIdx.x;
    const int lane = tid & 63;
    const int wave = tid >> 6;
    const int m0 = blockIdx.x * 128, n0 = blockIdx.y * 128;

    const int srow0 = wave * 32;
    const int lrow8 = lane >> 3;
    const int lcolS = (((lane & 7) ^ lrow8) << 3);

    const bf16* aPc[4];
    const bf16* bPc[4];
    short* aLc[4];
    short* bLc[4];
    #pragma unroll
    for (int c = 0; c < 4; c++) {
        aPc[c] = A + (size_t)(m0 + srow0 + c * 8 + lrow8) * K + lcolS;
        bPc[c] = Wt + (size_t)(n0 + srow0 + c * 8 + lrow8) * K + lcolS;
        aLc[c] = &As[(srow0 + c * 8) * 64];
        bLc[c] = &Bs[(srow0 + c * 8) * 64];
    }

    const int wm = (wave & 1) * 64, wn = (wave >> 1) * 64;
    const int fr = lane & 15, quad = lane >> 4;
    const int fr7 = fr & 7;

    floatx4 acc[4][4];
    #pragma unroll
    for (int i = 0; i < 4; i++)
        #pragma unroll
        for (int j = 0; j < 4; j++) acc[i][j] = (floatx4){0.f, 0.f, 0.f, 0.f};

    for (int k0 = 0; k0 < K; k0 += 64) {
        #pragma unroll
        for (int c = 0; c < 4; c++) {
            gl_lds16(aPc[c] + k0, aLc[c]);
            gl_lds16(bPc[c] + k0, bLc[c]);
        }
        __syncthreads();
        #pragma unroll
        for (int s = 0; s < 2; s++) {
            const int co = (((s * 4 + quad) ^ fr7) << 3);
            short8 af[4], bfv[4];
            #pragma unroll
            for (int i = 0; i < 4; i++) af[i] = *(const short8*)&As[(wm + i * 16 + fr) * 64 + co];
            #pragma unroll
            for (int j = 0; j < 4; j++) bfv[j] = *(const short8*)&Bs[(wn + j * 16 + fr) * 64 + co];
            #pragma unroll
            for (int i = 0; i < 4; i++)
                #pragma unroll
                for (int j = 0; j < 4; j++)
                    acc[i][j] = __builtin_amdgcn_mfma_f32_16x16x32_bf16(af[i], bfv[j], acc[i][j], 0, 0, 0);
        }
        __syncthreads();
    }

    if (MODE == 0) {
        #pragma unroll
        for (int j = 0; j < 4; j++) {
            int n = n0 + wn + j * 16 + fr;
            float bv = b1[n];
            #pragma unroll
            for (int i = 0; i < 4; i++) {
                int mb = m0 + wm + i * 16 + quad * 4;
                #pragma unroll
                for (int r = 0; r < 4; r++)
                    o1[(size_t)(mb + r) * Ncols + n] = f2b(acc[i][j][r] + bv);
            }
        }
    } else {  // MODE 1: [inp|D] with per-row rms scale
        if (n0 + wn < 512) {
            int b = (m0 + wm) >> 9;
            #pragma unroll
            for (int i = 0; i < 4; i++) {
                int mb = m0 + wm + i * 16 + quad * 4;
                float sclr[4];
                #pragma unroll
                for (int r = 0; r < 4; r++) sclr[r] = SCL[mb + r];
                #pragma unroll
                for (int j = 0; j < 4; j++) {
                    int n = n0 + wn + j * 16 + fr;
                    float bv = b1[n];
                    bf16* dst = o1 + ((size_t)b * PADL + n + 1) * 512;
                    int ci = mb & 511;
                    short4v pk;
                    #pragma unroll
                    for (int r = 0; r < 4; r++) pk[r] = f2s(acc[i][j][r] * sclr[r] + bv);
                    *(short4v*)(dst + ci) = pk;
                }
            }
        } else {
            #pragma unroll
            for (int i = 0; i < 4; i++) {
                int mb = m0 + wm + i * 16 + quad * 4;
                float sclr[4];
                #pragma unroll
                for (int r = 0; r < 4; r++) sclr[r] = SCL[mb + r];
                #pragma unroll
                for (int j = 0; j < 4; j++) {
                    int n = n0 + wn + j * 16 + fr;
                    float bv = b2[n - 512];
                    #pragma unroll
                    for (int r = 0; r < 4; r++)
                        o2[(size_t)(mb + r) * 512 + (n - 512)] =
                            f2b(silu_f(acc[i][j][r] * sclr[r] + bv));
                }
            }
        }
    }
}

// ---- cb GEMM: xco @ [fc2⊕fc3 interleaved], epilogue = cb atomics only. BK=64. ----
__global__ __launch_bounds__(256) void cbgemm_kernel(const bf16* __restrict__ A,
                                                     const bf16* __restrict__ Wt,
                                                     const float* __restrict__ b2,
                                                     const float* __restrict__ b3,
                                                     float* __restrict__ CBv) {
    __shared__ __align__(16) short As[128 * 64];
    __shared__ __align__(16) short Bs[128 * 64];
    const int tid = threadIdx.x;
    const int lane = tid & 63;
    const int wave = tid >> 6;
    const int m0 = blockIdx.x * 128, n0 = blockIdx.y * 128;

    const int srow0 = wave * 32;
    const int lrow8 = lane >> 3;
    const int lcolS = (((lane & 7) ^ lrow8) << 3);
    const bf16* aPc[4];
    const bf16* bPc[4];
    short* aLc[4];
    short* bLc[4];
    #pragma unroll
    for (int c = 0; c < 4; c++) {
        aPc[c] = A + (size_t)(m0 + srow0 + c * 8 + lrow8) * 512 + lcolS;
        bPc[c] = Wt + (size_t)(n0 + srow0 + c * 8 + lrow8) * 512 + lcolS;
        aLc[c] = &As[(srow0 + c * 8) * 64];
        bLc[c] = &Bs[(srow0 + c * 8) * 64];
    }

    const int wm = (wave & 1) * 64, wn = (wave >> 1) * 64;
    const int fr = lane & 15, quad = lane >> 4;
    const int fr7 = fr & 7;

    floatx4 acc[4][4];
    #pragma unroll
    for (int i = 0; i < 4; i++)
        #pragma unroll
        for (int j = 0; j < 4; j++) acc[i][j] = (floatx4){0.f, 0.f, 0.f, 0.f};

    for (int k0 = 0; k0 < 512; k0 += 64) {
        #pragma unroll
        for (int c = 0; c < 4; c++) {
            gl_lds16(aPc[c] + k0, aLc[c]);
            gl_lds16(bPc[c] + k0, bLc[c]);
        }
        __syncthreads();
        #pragma unroll
        for (int s = 0; s < 2; s++) {
            const int co = (((s * 4 + quad) ^ fr7) << 3);
            short8 af[4], bfv[4];
            #pragma unroll
            for (int i = 0; i < 4; i++) af[i] = *(const short8*)&As[(wm + i * 16 + fr) * 64 + co];
            #pragma unroll
            for (int j = 0; j < 4; j++) bfv[j] = *(const short8*)&Bs[(wn + j * 16 + fr) * 64 + co];
            #pragma unroll
            for (int i = 0; i < 4; i++)
                #pragma unroll
                for (int j = 0; j < 4; j++)
                    acc[i][j] = __builtin_amdgcn_mfma_f32_16x16x32_bf16(af[i], bfv[j], acc[i][j], 0, 0, 0);
        }
        __syncthreads();
    }
    int nnb = n0 + wn;
    float bv[4];
    #pragma unroll
    for (int j = 0; j < 4; j++) {
        int nn = nnb + j * 16 + fr;
        int c = nn >> 1;
        bv[j] = (fr & 1) ? b3[c] : b2[c];
    }
    #pragma unroll
    for (int i = 0; i < 4; i++) {
        #pragma unroll
        for (int r = 0; r < 4; r++) {
            float s = 0.f;
            #pragma unroll
            for (int j = 0; j < 4; j++) {
                float v = acc[i][j][r] + bv[j];
                s += v * __shfl_xor(v, 1);
            }
            s += __shfl_xor(s, 2);
            s += __shfl_xor(s, 4);
            s += __shfl_xor(s, 8);
            if (fr == 0)
                atomicAdd(&CBv[m0 + wm + i * 16 + quad * 4 + r], s * 0.5f);
        }
    }
}

// ---- fc1 GEMM with FUSED s6 gate epilogue. BK=64. ----
__global__ __launch_bounds__(256) void fc1gate_kernel(const bf16* __restrict__ A,
                                                      const bf16* __restrict__ Wt,
                                                      const float* __restrict__ b1,
                                                      const float* __restrict__ CBv,
                                                      const bf16* __restrict__ Xres,
                                                      bf16* __restrict__ G) {
    __shared__ __align__(16) short As[128 * 64];
    __shared__ __align__(16) short Bs[128 * 64];
    const int tid = threadIdx.x;
    const int lane = tid & 63;
    const int wave = tid >> 6;
    const int m0 = blockIdx.x * 128, n0 = blockIdx.y * 128;

    const int srow0 = wave * 32;
    const int lrow8 = lane >> 3;
    const int lcolS = (((lane & 7) ^ lrow8) << 3);
    const bf16* aPc[4];
    const bf16* bPc[4];
    short* aLc[4];
    short* bLc[4];
    #pragma unroll
    for (int c = 0; c < 4; c++) {
        aPc[c] = A + (size_t)(m0 + srow0 + c * 8 + lrow8) * 512 + lcolS;
        bPc[c] = Wt + (size_t)(n0 + srow0 + c * 8 + lrow8) * 512 + lcolS;
        aLc[c] = &As[(srow0 + c * 8) * 64];
        bLc[c] = &Bs[(srow0 + c * 8) * 64];
    }

    const int wm = (wave & 1) * 64, wn = (wave >> 1) * 64;
    const int fr = lane & 15, quad = lane >> 4;
    const int fr7 = fr & 7;

    floatx4 acc[4][4];
    #pragma unroll
    for (int i = 0; i < 4; i++)
        #pragma unroll
        for (int j = 0; j < 4; j++) acc[i][j] = (floatx4){0.f, 0.f, 0.f, 0.f};

    for (int k0 = 0; k0 < 512; k0 += 64) {
        #pragma unroll
        for (int c = 0; c < 4; c++) {
            gl_lds16(aPc[c] + k0, aLc[c]);
            gl_lds16(bPc[c] + k0, bLc[c]);
        }
        __syncthreads();
        #pragma unroll
        for (int s = 0; s < 2; s++) {
            const int co = (((s * 4 + quad) ^ fr7) << 3);
            short8 af[4], bfv[4];
            #pragma unroll
            for (int i = 0; i < 4; i++) af[i] = *(const short8*)&As[(wm + i * 16 + fr) * 64 + co];
            #pragma unroll
            for (int j = 0; j < 4; j++) bfv[j] = *(const short8*)&Bs[(wn + j * 16 + fr) * 64 + co];
            #pragma unroll
            for (int i = 0; i < 4; i++)
                #pragma unroll
                for (int j = 0; j < 4; j++)
                    acc[i][j] = __builtin_amdgcn_mfma_f32_16x16x32_bf16(af[i], bfv[j], acc[i][j], 0, 0, 0);
        }
        __syncthreads();
    }
    #pragma unroll
    for (int i = 0; i < 4; i++) {
        int mb = m0 + wm + i * 16 + quad * 4;
        float cbr[4];
        #pragma unroll
        for (int r = 0; r < 4; r++) cbr[r] = CBv[mb + r];
        #pragma unroll
        for (int j = 0; j < 4; j++) {
            int n = n0 + wn + j * 16 + fr;
            float bv = b1[n];
            #pragma unroll
            for (int r = 0; r < 4; r++) {
                size_t off = (size_t)(mb + r) * 512 + n;
                float delta = softplus_f(acc[i][j][r] + bv);
                float xssm = delta * b2f(A[off]) * cbr[r];
                G[off] = f2b(silu_f(xssm) * b2f(Xres[off]));
            }
        }
    }
}

// ---- conv as implicit MFMA GEMM + CBv zeroing at entry. BK=64. ----
__global__ __launch_bounds__(256) void conv_mfma_kernel(const bf16* __restrict__ Wc,
                                                        const bf16* __restrict__ xpT,
                                                        const float* __restrict__ bias,
                                                        bf16* __restrict__ Out,
                                                        float* __restrict__ CBvZ) {
    __shared__ __align__(16) short As[3 * 128 * 64];
    __shared__ __align__(16) short Bs[144 * 64];
    const int tid = threadIdx.x;
    const int lane = tid & 63;
    const int wave = tid >> 6;
    int bx = blockIdx.x;
    if (bx < 128 && tid < 128) CBvZ[bx * 128 + tid] = 0.0f;
    int xcd = bx & 7, g = bx >> 3;
    int mt = g & 3;
    int id = xcd * 16 + (g >> 2);
    int nt = id & 3, b = id >> 2;
    const int m0 = mt * 128, n0 = nt * 128;
    const bf16* xb = xpT + (size_t)b * PADL * 512;

    const int lrow8 = lane >> 3;
    const int lcolS = (((lane & 7) ^ lrow8) << 3);
    const int wm = (wave & 1) * 64, wn = (wave >> 1) * 64;
    const int fr = lane & 15, quad = lane >> 4;
    const int fr7 = fr & 7;

    floatx4 acc[4][4];
    #pragma unroll
    for (int i = 0; i < 4; i++)
        #pragma unroll
        for (int j = 0; j < 4; j++) acc[i][j] = (floatx4){0.f, 0.f, 0.f, 0.f};

    for (int k0 = 0; k0 < 512; k0 += 64) {
        // A: 3 taps x 128 rows = 48 chunks of 8 rows
        for (int ga = wave; ga < 48; ga += 4) {
            int tap = ga >> 4, rg = ga & 15;
            gl_lds16(Wc + (size_t)tap * 262144 + (size_t)(m0 + rg * 8 + lrow8) * 512 + k0 + lcolS,
                     &As[tap * 8192 + rg * 512]);
        }
        // B: 144 rows = 18 chunks of 8 rows
        for (int gb = wave; gb < 18; gb += 4) {
            gl_lds16(xb + (size_t)(n0 + gb * 8 + lrow8) * 512 + k0 + lcolS, &Bs[gb * 512]);
        }
        __syncthreads();
        #pragma unroll
        for (int s = 0; s < 2; s++) {
            const int sq = s * 4 + quad;
            #pragma unroll
            for (int tap = 0; tap < 3; tap++) {
                const int coA = ((sq ^ fr7) << 3);
                const int coB = ((sq ^ ((fr + tap) & 7)) << 3);
                short8 af[4], bfv[4];
                #pragma unroll
                for (int i = 0; i < 4; i++)
                    af[i] = *(const short8*)&As[tap * 8192 + (wm + i * 16 + fr) * 64 + coA];
                #pragma unroll
                for (int j = 0; j < 4; j++)
                    bfv[j] = *(const short8*)&Bs[(wn + j * 16 + fr + tap) * 64 + coB];
                #pragma unroll
                for (int i = 0; i < 4; i++)
                    #pragma unroll
                    for (int j = 0; j < 4; j++)
                        acc[i][j] = __builtin_amdgcn_mfma_f32_16x16x32_bf16(af[i], bfv[j], acc[i][j], 0, 0, 0);
            }
        }
        __syncthreads();
    }
    bf16* ob = Out + (size_t)b * CF * CT2;
    #pragma unroll
    for (int i = 0; i < 4; i++) {
        int mb = m0 + wm + i * 16 + quad * 4;
        #pragma unroll
        for (int r = 0; r < 4; r++) {
            float bv = bias[mb + r];
            #pragma unroll
            for (int j = 0; j < 4; j++) {
                int n = n0 + wn + j * 16 + fr;
                ob[(size_t)(mb + r) * CT2 + n] = f2b(silu_f(acc[i][j][r] + bv));
            }
        }
    }
}

// ---- out-GEMM (K=512, N=256) + rms scale computation (NOT applied). BK=64. ----
__global__ __launch_bounds__(256) void gemm_scl_kernel(const bf16* __restrict__ A,
                                                       const bf16* __restrict__ Wt,
                                                       const float* __restrict__ bias,
                                                       bf16* __restrict__ Xo,
                                                       float* __restrict__ SCL) {
    __shared__ __align__(16) short As[64 * 64];
    __shared__ __align__(16) short Bs[256 * 64];
    __shared__ float red[4][64];
    const int tid = threadIdx.x;
    const int lane = tid & 63;
    const int wave = tid >> 6;
    const int m0 = blockIdx.x * 64;

    const int lrow8 = lane >> 3;
    const int lcolS = (((lane & 7) ^ lrow8) << 3);
    const int wn = wave * 64;
    const int fr = lane & 15, quad = lane >> 4;
    const int fr7 = fr & 7;

    floatx4 acc[4][4];
    #pragma unroll
    for (int i = 0; i < 4; i++)
        #pragma unroll
        for (int j = 0; j < 4; j++) acc[i][j] = (floatx4){0.f, 0.f, 0.f, 0.f};

    for (int k0 = 0; k0 < 512; k0 += 64) {
        // A: 64 rows = 8 chunks; B: 256 rows = 32 chunks
        for (int c = wave; c < 8; c += 4)
            gl_lds16(A + (size_t)(m0 + c * 8 + lrow8) * 512 + k0 + lcolS, &As[c * 512]);
        for (int c = wave; c < 32; c += 4)
            gl_lds16(Wt + (size_t)(c * 8 + lrow8) * 512 + k0 + lcolS, &Bs[c * 512]);
        __syncthreads();
        #pragma unroll
        for (int s = 0; s < 2; s++) {
            const int co = (((s * 4 + quad) ^ fr7) << 3);
            short8 af[4], bfv[4];
            #pragma unroll
            for (int i = 0; i < 4; i++) af[i] = *(const short8*)&As[(i * 16 + fr) * 64 + co];
            #pragma unroll
            for (int j = 0; j < 4; j++) bfv[j] = *(const short8*)&Bs[(wn + j * 16 + fr) * 64 + co];
            #pragma unroll
            for (int i = 0; i < 4; i++)
                #pragma unroll
                for (int j = 0; j < 4; j++)
                    acc[i][j] = __builtin_amdgcn_mfma_f32_16x16x32_bf16(af[i], bfv[j], acc[i][j], 0, 0, 0);
        }
        __syncthreads();
    }
    #pragma unroll
    for (int j = 0; j < 4; j++) {
        float bv = bias[wn + j * 16 + fr];
        #pragma unroll
        for (int i = 0; i < 4; i++)
            #pragma unroll
            for (int r = 0; r < 4; r++) acc[i][j][r] += bv;
    }
    #pragma unroll
    for (int i = 0; i < 4; i++) {
        #pragma unroll
        for (int r = 0; r < 4; r++) {
            float s = 0.f;
            #pragma unroll
            for (int j = 0; j < 4; j++) s += acc[i][j][r] * acc[i][j][r];
            #pragma unroll
            for (int o = 8; o > 0; o >>= 1) s += __shfl_xor(s, o);
            if (fr == 0) red[wave][i * 16 + quad * 4 + r] = s;
        }
    }
    __syncthreads();
    if (tid < 64) {
        float tot = red[0][tid] + red[1][tid] + red[2][tid] + red[3][tid];
        SCL[m0 + tid] = rsqrtf(tot * (1.0f / CT) + 1e-5f);
    }
    #pragma unroll
    for (int j = 0; j < 4; j++) {
        int n = wn + j * 16 + fr;
        #pragma unroll
        for (int i = 0; i < 4; i++) {
            int rl = i * 16 + quad * 4;
            #pragma unroll
            for (int r = 0; r < 4; r++)
                Xo[(size_t)(m0 + rl + r) * CT + n] = f2b(acc[i][j][r]);
        }
    }
}

// ---- proj GEMM (K=256, N=256) with fused de-norm + transpose to fp32 out. BK=64. ----
__global__ __launch_bounds__(256) void proj_out_kernel(const bf16* __restrict__ A,
                                                       const bf16* __restrict__ Wt,
                                                       const float* __restrict__ bias,
                                                       const float* __restrict__ means,
                                                       const float* __restrict__ stdev,
                                                       float* __restrict__ out) {
    __shared__ __align__(16) short As[128 * 64];
    __shared__ __align__(16) short Bs[128 * 64];
    const int tid = threadIdx.x;
    const int lane = tid & 63;
    const int wave = tid >> 6;
    const int m0 = blockIdx.x * 128, n0 = blockIdx.y * 128;

    const int srow0 = wave * 32;
    const int lrow8 = lane >> 3;
    const int lcolS = (((lane & 7) ^ lrow8) << 3);
    const bf16* aPc[4];
    const bf16* bPc[4];
    short* aLc[4];
    short* bLc[4];
    #pragma unroll
    for (int c = 0; c < 4; c++) {
        aPc[c] = A + (size_t)(m0 + srow0 + c * 8 + lrow8) * 256 + lcolS;
        bPc[c] = Wt + (size_t)(n0 + srow0 + c * 8 + lrow8) * 256 + lcolS;
        aLc[c] = &As[(srow0 + c * 8) * 64];
        bLc[c] = &Bs[(srow0 + c * 8) * 64];
    }

    const int wm = (wave & 1) * 64, wn = (wave >> 1) * 64;
    const int fr = lane & 15, quad = lane >> 4;
    const int fr7 = fr & 7;

    floatx4 acc[4][4];
    #pragma unroll
    for (int i = 0; i < 4; i++)
        #pragma unroll
        for (int j = 0; j < 4; j++) acc[i][j] = (floatx4){0.f, 0.f, 0.f, 0.f};

    for (int k0 = 0; k0 < 256; k0 += 64) {
        #pragma unroll
        for (int c = 0; c < 4; c++) {
            gl_lds16(aPc[c] + k0, aLc[c]);
            gl_lds16(bPc[c] + k0, bLc[c]);
        }
        __syncthreads();
        #pragma unroll
        for (int s = 0; s < 2; s++) {
            const int co = (((s * 4 + quad) ^ fr7) << 3);
            short8 af[4], bfv[4];
            #pragma unroll
            for (int i = 0; i < 4; i++) af[i] = *(const short8*)&As[(wm + i * 16 + fr) * 64 + co];
            #pragma unroll
            for (int j = 0; j < 4; j++) bfv[j] = *(const short8*)&Bs[(wn + j * 16 + fr) * 64 + co];
            #pragma unroll
            for (int i = 0; i < 4; i++)
                #pragma unroll
                for (int j = 0; j < 4; j++)
                    acc[i][j] = __builtin_amdgcn_mfma_f32_16x16x32_bf16(af[i], bfv[j], acc[i][j], 0, 0, 0);
        }
        __syncthreads();
    }
    #pragma unroll
    for (int j = 0; j < 4; j++) {
        int t = n0 + wn + j * 16 + fr;
        float bv = bias[t];
        #pragma unroll
        for (int i = 0; i < 4; i++) {
            int mb = m0 + wm + i * 16 + quad * 4;
            int b = mb >> 9;
            int nv = mb & 511;
            if (nv < CN) {
                floatx4 o;
                #pragma unroll
                for (int r = 0; r < 4; r++) {
                    int sn = b * CN + nv + r;
                    o[r] = (acc[i][j][r] + bv) * stdev[sn] + means[sn];
                }
                *(floatx4*)(out + ((size_t)(b * CT + t)) * CN + nv) = o;
            }
        }
    }
}

extern "C" void kernel_launch(void* const* d_in, const int* in_sizes, int n_in,
                              void* d_out, int out_size, void* d_ws, size_t ws_size,
                              hipStream_t stream) {
    const float* x_enc  = (const float*)d_in[0];
    const float* x_mark = (const float*)d_in[1];
    const float* norm_w = (const float*)d_in[4];
    const float* inp_W  = (const float*)d_in[5];
    const float* inp_b  = (const float*)d_in[6];
    const float* conv_W = (const float*)d_in[7];
    const float* conv_b = (const float*)d_in[8];
    const float* convlin_W = (const float*)d_in[9];
    const float* convlin_b = (const float*)d_in[10];
    const float* fc1_W = (const float*)d_in[11];
    const float* fc1_b = (const float*)d_in[12];
    const float* fc2_W = (const float*)d_in[13];
    const float* fc2_b = (const float*)d_in[14];
    const float* fc3_W = (const float*)d_in[15];
    const float* fc3_b = (const float*)d_in[16];
    const float* D_W   = (const float*)d_in[17];
    const float* D_b   = (const float*)d_in[18];
    const float* out_W = (const float*)d_in[19];
    const float* out_b = (const float*)d_in[20];
    const float* proj_W = (const float*)d_in[21];
    const float* proj_b = (const float*)d_in[22];

    // ---- workspace layout ----
    char* ws = (char*)d_ws;
    float* MEANS = (float*)(ws);
    float* STDEV = (float*)(ws + 65536);
    float* CBv   = (float*)(ws + 131072);
    float* SCL   = (float*)(ws + 196608);    // 64 KB slot (16384 fp32)
    bf16* wt = (bf16*)(ws + 262144);
    bf16* wt_g1      = wt;                   // 3 x [1024][256]  (nw-folded inp^T | D^T)
    bf16* wt_g3      = wt + 786432;          // 3 x [fc1^T | fc2⊕fc3]
    bf16* wt_convlin = wt + 2359296;
    bf16* wt_out     = wt + 3145728;
    bf16* wt_proj    = wt + 3538944;
    bf16* wt_conv    = wt + 3604480;         // 3 x [3][512][512]
    bf16* xpT = (bf16*)(ws + 12189696);      // [32][528][512]
    const size_t POOLB = 16777216;
    bf16* pool[4] = {
        (bf16*)(ws + 29491200),
        (bf16*)(ws + 29491200 + POOLB),
        (bf16*)(ws + 29491200 + 2 * POOLB),
        (bf16*)(ws + 29491200 + 3 * POOLB),
    };
    float* out = (float*)d_out;

    // ---- single merged prepack (weights + conv + pads + CBv zero) ----
    P8 p;
    p.s[0] = inp_W;  p.d[0] = wt_g1;
    p.s[1] = D_W;    p.d[1] = wt_g1 + 131072;
    p.s[2] = fc1_W;  p.d[2] = wt_g3;
    p.s[3] = fc2_W;  p.d[3] = wt_g3 + 262144;
    p.s[4] = fc3_W;  p.d[4] = wt_g3 + 262144;
    p.s[5] = convlin_W; p.d[5] = wt_convlin;
    p.s[6] = out_W;  p.d[6] = wt_out;
    p.s[7] = proj_W; p.d[7] = wt_proj;
    int convBlocks = (CONVN + 32768 + MROWS + 255) / 256;
    prepack_all_kernel<<<MTILES + convBlocks, 256, 0, stream>>>(
        p, norm_w, conv_W, wt_conv, xpT, CBv);

    // ---- stats + build: raw x -> pool[0].lo, rms scale -> SCL ----
    buildx_kernel<<<256, 256, 0, stream>>>(x_enc, x_mark, MEANS, STDEV, pool[0], SCL);

    // 4-pool rotation
    int ia = 0, ico = 1, ires = 2, iout = 3;
    for (int i = 0; i < 3; i++) {
        bf16* A  = pool[ia];
        bf16* XCO = pool[ico];
        bf16* XRES = pool[ires];
        bf16* OUTP = pool[iout];

        // [xp|xres] = (x*scl) @ [nw∘inp | nw∘D] + b : xp -> xpT^T, xres -> XRES
        mgemm_kernel<1><<<dim3(128, 8), 256, 0, stream>>>(
            A, wt_g1 + (size_t)i * 262144, inp_b + i * CT2, D_b + i * CT2, SCL,
            xpT, XRES, 256, 1024);
        // xc = silu(conv(xp)) -> A ; zeroes CBv
        conv_mfma_kernel<<<512, 256, 0, stream>>>(wt_conv + (size_t)i * 786432, xpT,
                                                  conv_b + i * CF, A, CBv);
        // xco = xc @ convlin + b -> XCO
        mgemm_kernel<0><<<dim3(128, 4), 256, 0, stream>>>(
            A, wt_convlin + (size_t)i * 262144, convlin_b + i * CT2, nullptr, nullptr,
            XCO, nullptr, 512, 512);
        // cb atomics
        cbgemm_kernel<<<dim3(128, 4), 256, 0, stream>>>(
            XCO, wt_g3 + (size_t)i * 524288 + 262144, fc2_b + i * CT, fc3_b + i * CT, CBv);
        // g = gate(fc1, xco, cb, xres) -> A
        fc1gate_kernel<<<dim3(128, 4), 256, 0, stream>>>(
            XCO, wt_g3 + (size_t)i * 524288, fc1_b + i * CT2, CBv, XRES, A);
        // x_next = g @ out_W + b -> OUTP.lo ; scl -> SCL
        gemm_scl_kernel<<<256, 256, 0, stream>>>(
            A, wt_out + (size_t)i * 131072, out_b + i * CT, OUTP, SCL);

        int na = iout, nco = ia, nres = ico, nout = ires;
        ia = na; ico = nco; ires = nres; iout = nout;
    }

    // x_final in pool[ia].lo. dec = x @ proj_W + b, de-norm + transpose to out
    proj_out_kernel<<<dim3(128, 2), 256, 0, stream>>>(
        pool[ia], wt_proj, proj_b, MEANS, STDEV, out);
}

// Round 3
// 528.183 us; speedup vs baseline: 1.1149x; 1.0763x over previous
//
#include <hip/hip_runtime.h>
#include <hip/hip_bf16.h>
#include <math.h>

typedef __hip_bfloat16 bf16;
typedef short short8 __attribute__((ext_vector_type(8)));
typedef short short4v __attribute__((ext_vector_type(4)));
typedef float floatx4 __attribute__((ext_vector_type(4)));

constexpr int CB_ = 32;
constexpr int CT = 256;
constexpr int CF = 512;
constexpr int CN = 508;
constexpr int CM = 4;
constexpr int CT2 = 512;
constexpr int MROWS = CB_ * CF;  // 16384
constexpr int PADL = 528;

__device__ __forceinline__ float b2f(bf16 v) { return __bfloat162float(v); }
__device__ __forceinline__ bf16 f2b(float v) { return __float2bfloat16(v); }
__device__ __forceinline__ short f2s(float v) {
    bf16 t = __float2bfloat16(v);
    return __builtin_bit_cast(short, t);
}
__device__ __forceinline__ float silu_f(float x) { return x / (1.0f + __expf(-x)); }
__device__ __forceinline__ float softplus_f(float x) {
    return fmaxf(x, 0.0f) + __logf(1.0f + __expf(-fabsf(x)));
}

__device__ __forceinline__ void gl_lds16(const bf16* g, short* l) {
    __builtin_amdgcn_global_load_lds(
        (const __attribute__((address_space(1))) unsigned int*)(g),
        (__attribute__((address_space(3))) unsigned int*)(l), 16, 0, 0);
}

// BK=64 LDS tiles: [rows][64 shorts] (128B rows). gl_lds16 covers 8 rows x 64 cols.
// XOR swizzle: LDS slot (row, col16) holds global (row, col16 ^ (row&7)).
// Source addr per lane: row += lane>>3 ; col16 = (lane&7) ^ (lane>>3).
// ds_read col16' = (s*4+quad) ^ (row&7) recovers k = s*32 + quad*8.

// ---- ALL prepack in one kernel: 8 weight transposes (+nw folding for inp/D),
// conv weight pack, xpT pad rows, CBv zero.
constexpr int CONVN = 3 * 3 * 512 * 512;  // 2359296
constexpr int MTILES = 3520;
struct P8 { const float* s[8]; bf16* d[8]; };
__global__ __launch_bounds__(256) void prepack_all_kernel(P8 p, const float* __restrict__ nw,
                                                          const float* __restrict__ convW,
                                                          bf16* __restrict__ convD,
                                                          bf16* __restrict__ xpT,
                                                          float* __restrict__ CBv) {
    int bid = blockIdx.x;
    if (bid >= MTILES) {
        int idx = (bid - MTILES) * 256 + threadIdx.x;
        if (idx < CONVN) {
            int ci = idx & 511;
            int co = (idx >> 9) & 511;
            int it = idx >> 18;
            int tap = it % 3, ib = it / 3;
            convD[idx] = f2b(convW[(((size_t)(ib * 512 + co)) * 512 + ci) * 3 + tap]);
        } else if (idx < CONVN + 32768) {
            int j = idx - CONVN;
            int ci = j & 511;
            int w = (j >> 9) & 1;
            int b = j >> 10;
            xpT[((size_t)b * PADL + (w ? 513 : 0)) * 512 + ci] = f2b(0.0f);
        } else if (idx < CONVN + 32768 + MROWS) {
            CBv[idx - CONVN - 32768] = 0.0f;
        }
        return;
    }
    const int Ks[8]   = {256, 256, 512, 512, 512, 512, 512, 256};
    const int Ns[8]   = {512, 512, 512, 256, 256, 512, 256, 256};
    const int zs[8]   = {3, 3, 3, 3, 3, 3, 3, 1};
    const int dstr[8] = {262144, 262144, 524288, 524288, 524288, 262144, 131072, 65536};
    const int rml[8]  = {1, 1, 1, 2, 2, 1, 1, 1};
    const int rad[8]  = {0, 0, 0, 0, 1, 0, 0, 0};
    int m = 0, acc = 0;
    for (m = 0; m < 8; m++) {
        int c = (Ns[m] >> 5) * (Ks[m] >> 5) * zs[m];
        if (bid < acc + c) break;
        acc += c;
    }
    int lid = bid - acc;
    int K = Ks[m], N = Ns[m];
    int tx = N >> 5, ty = K >> 5;
    int z = lid / (tx * ty), rem = lid % (tx * ty);
    int k0 = (rem / tx) * 32, n0 = (rem % tx) * 32;
    const float* s = p.s[m] + (size_t)z * K * N;
    bf16* d = p.d[m] + (size_t)z * dstr[m];
    int mul = rml[m], add = rad[m];
    bool fold = (m <= 1);  // inp_W, D_W: fold nw_z into K-rows
    __shared__ float Ts[32][33];
    for (int e = threadIdx.x; e < 1024; e += 256) {
        int r = e >> 5, c = e & 31;
        float v = s[(size_t)(k0 + r) * N + n0 + c];
        if (fold) v *= nw[z * 256 + k0 + r];
        Ts[r][c] = v;
    }
    __syncthreads();
    for (int e = threadIdx.x; e < 1024; e += 256) {
        int r = e >> 5, c = e & 31;
        d[(size_t)((n0 + r) * mul + add) * K + k0 + c] = f2b(Ts[c][r]);
    }
}

// ---- fused stats + build_x (iter 0): writes RAW x (bf16) + rms scale SCL ----
__global__ __launch_bounds__(256) void buildx_kernel(
    const float* __restrict__ xe, const float* __restrict__ xm,
    float* __restrict__ means, float* __restrict__ stdev,
    bf16* __restrict__ X0, float* __restrict__ SCL) {
    __shared__ float L[256][65];
    __shared__ float red_s[4][64], red_q[4][64];
    __shared__ float stat_m[64], stat_i[64];
    int blk = blockIdx.x;
    int b = blk >> 3, f0 = (blk & 7) * 64;
    int tid = threadIdx.x;
    int j = tid & 63, tq = tid >> 6;
    int f = f0 + j;
    float ps = 0.f, pq = 0.f;
    const float* xep = xe + (size_t)b * CT * CN + f;
    const float* xmp = xm + (size_t)b * CT * CM + (f - CN);
    #pragma unroll 4
    for (int tt = 0; tt < 64; tt++) {
        int t = tq * 64 + tt;
        float v = (f < CN) ? xep[(size_t)t * CN] : xmp[(size_t)t * CM];
        L[t][j] = v;
        ps += v;
        pq += v * v;
    }
    red_s[tq][j] = ps;
    red_q[tq][j] = pq;
    __syncthreads();
    if (tid < 64) {
        int ff = f0 + tid;
        float s = red_s[0][tid] + red_s[1][tid] + red_s[2][tid] + red_s[3][tid];
        float q = red_q[0][tid] + red_q[1][tid] + red_q[2][tid] + red_q[3][tid];
        float mean, isd, msq;
        if (ff < CN) {
            mean = s * (1.0f / 256.0f);
            float var = fmaxf(q * (1.0f / 256.0f) - mean * mean, 0.0f);
            float sd = sqrtf(var + 1e-5f);
            isd = 1.0f / sd;
            means[b * CN + ff] = mean;
            stdev[b * CN + ff] = sd;
            msq = var / (var + 1e-5f);
        } else {
            mean = 0.0f;
            isd = 1.0f;
            msq = q * (1.0f / 256.0f);
        }
        stat_m[tid] = mean;
        stat_i[tid] = isd;
        SCL[b * 512 + ff] = rsqrtf(msq + 1e-5f);
    }
    __syncthreads();
    bf16* outp = X0 + ((size_t)(b * 512 + f0)) * 256;
    int t = tid;
    #pragma unroll 4
    for (int fp = 0; fp < 64; fp++) {
        float val = (L[t][fp] - stat_m[fp]) * stat_i[fp];
        outp[(size_t)fp * 256 + t] = f2b(val);
    }
}

// ---- MFMA GEMM 128x128 tile, BK=64. MODE 1: [inp|D] with per-row SCL epilogue. ----
template <int MODE>
__global__ __launch_bounds__(256) void mgemm_kernel(const bf16* __restrict__ A,
                                                    const bf16* __restrict__ Wt,
                                                    const float* __restrict__ b1,
                                                    const float* __restrict__ b2,
                                                    const float* __restrict__ SCL,
                                                    bf16* __restrict__ o1,
                                                    bf16* __restrict__ o2,
                                                    int K, int Ncols) {
    __shared__ __align__(16) short As[128 * 64];
    __shared__ __align__(16) short Bs[128 * 64];
    const int tid = threadIdx.x;
    const int lane = tid & 63;
    const int wave = tid >> 6;
    const int m0 = blockIdx.x * 128, n0 = blockIdx.y * 128;

    const int srow0 = wave * 32;
    const int lrow8 = lane >> 3;
    const int lcolS = (((lane & 7) ^ lrow8) << 3);

    const bf16* aPc[4];
    const bf16* bPc[4];
    short* aLc[4];
    short* bLc[4];
    #pragma unroll
    for (int c = 0; c < 4; c++) {
        aPc[c] = A + (size_t)(m0 + srow0 + c * 8 + lrow8) * K + lcolS;
        bPc[c] = Wt + (size_t)(n0 + srow0 + c * 8 + lrow8) * K + lcolS;
        aLc[c] = &As[(srow0 + c * 8) * 64];
        bLc[c] = &Bs[(srow0 + c * 8) * 64];
    }

    const int wm = (wave & 1) * 64, wn = (wave >> 1) * 64;
    const int fr = lane & 15, quad = lane >> 4;
    const int fr7 = fr & 7;

    floatx4 acc[4][4];
    #pragma unroll
    for (int i = 0; i < 4; i++)
        #pragma unroll
        for (int j = 0; j < 4; j++) acc[i][j] = (floatx4){0.f, 0.f, 0.f, 0.f};

    for (int k0 = 0; k0 < K; k0 += 64) {
        #pragma unroll
        for (int c = 0; c < 4; c++) {
            gl_lds16(aPc[c] + k0, aLc[c]);
            gl_lds16(bPc[c] + k0, bLc[c]);
        }
        __syncthreads();
        #pragma unroll
        for (int s = 0; s < 2; s++) {
            const int co = (((s * 4 + quad) ^ fr7) << 3);
            short8 af[4], bfv[4];
            #pragma unroll
            for (int i = 0; i < 4; i++) af[i] = *(const short8*)&As[(wm + i * 16 + fr) * 64 + co];
            #pragma unroll
            for (int j = 0; j < 4; j++) bfv[j] = *(const short8*)&Bs[(wn + j * 16 + fr) * 64 + co];
            #pragma unroll
            for (int i = 0; i < 4; i++)
                #pragma unroll
                for (int j = 0; j < 4; j++)
                    acc[i][j] = __builtin_amdgcn_mfma_f32_16x16x32_bf16(af[i], bfv[j], acc[i][j], 0, 0, 0);
        }
        __syncthreads();
    }

    if (MODE == 0) {
        #pragma unroll
        for (int j = 0; j < 4; j++) {
            int n = n0 + wn + j * 16 + fr;
            float bv = b1[n];
            #pragma unroll
            for (int i = 0; i < 4; i++) {
                int mb = m0 + wm + i * 16 + quad * 4;
                #pragma unroll
                for (int r = 0; r < 4; r++)
                    o1[(size_t)(mb + r) * Ncols + n] = f2b(acc[i][j][r] + bv);
            }
        }
    } else {  // MODE 1: [inp|D] with per-row rms scale
        if (n0 + wn < 512) {
            int b = (m0 + wm) >> 9;
            #pragma unroll
            for (int i = 0; i < 4; i++) {
                int mb = m0 + wm + i * 16 + quad * 4;
                float sclr[4];
                #pragma unroll
                for (int r = 0; r < 4; r++) sclr[r] = SCL[mb + r];
                #pragma unroll
                for (int j = 0; j < 4; j++) {
                    int n = n0 + wn + j * 16 + fr;
                    float bv = b1[n];
                    bf16* dst = o1 + ((size_t)b * PADL + n + 1) * 512;
                    int ci = mb & 511;
                    short4v pk;
                    #pragma unroll
                    for (int r = 0; r < 4; r++) pk[r] = f2s(acc[i][j][r] * sclr[r] + bv);
                    *(short4v*)(dst + ci) = pk;
                }
            }
        } else {
            #pragma unroll
            for (int i = 0; i < 4; i++) {
                int mb = m0 + wm + i * 16 + quad * 4;
                float sclr[4];
                #pragma unroll
                for (int r = 0; r < 4; r++) sclr[r] = SCL[mb + r];
                #pragma unroll
                for (int j = 0; j < 4; j++) {
                    int n = n0 + wn + j * 16 + fr;
                    float bv = b2[n - 512];
                    #pragma unroll
                    for (int r = 0; r < 4; r++)
                        o2[(size_t)(mb + r) * 512 + (n - 512)] =
                            f2b(silu_f(acc[i][j][r] * sclr[r] + bv));
                }
            }
        }
    }
}

// ---- unified 128x64-tile GEMM (BK=64, 24KB LDS, 4 blocks/CU).
// EPI 0: plain store (+b1). EPI 1: cb pair-product atomics (b1=fc2_b,b2=fc3_b).
// EPI 2: s6 gate (b1=fc1_b, CBin, Xres, o1=G). EPI 3: proj de-norm fp32 out. ----
template <int EPI>
__global__ __launch_bounds__(256) void g64_kernel(const bf16* __restrict__ A,
                                                  const bf16* __restrict__ Wt,
                                                  int K,
                                                  const float* __restrict__ b1,
                                                  const float* __restrict__ b2,
                                                  const float* __restrict__ CBin,
                                                  const bf16* __restrict__ Xres,
                                                  float* __restrict__ CBout,
                                                  bf16* __restrict__ o1,
                                                  int Ncols,
                                                  const float* __restrict__ means,
                                                  const float* __restrict__ stdev,
                                                  float* __restrict__ outf) {
    __shared__ __align__(16) short As[128 * 64];
    __shared__ __align__(16) short Bs[64 * 64];
    const int tid = threadIdx.x;
    const int lane = tid & 63;
    const int wave = tid >> 6;
    const int m0 = blockIdx.x * 128, n0 = blockIdx.y * 64;

    const int lrow8 = lane >> 3;
    const int lcolS = (((lane & 7) ^ lrow8) << 3);
    const int wm = (wave & 1) * 64, wn = (wave >> 1) * 32;
    const int fr = lane & 15, quad = lane >> 4;
    const int fr7 = fr & 7;

    floatx4 acc[4][2];
    #pragma unroll
    for (int i = 0; i < 4; i++)
        #pragma unroll
        for (int j = 0; j < 2; j++) acc[i][j] = (floatx4){0.f, 0.f, 0.f, 0.f};

    for (int k0 = 0; k0 < K; k0 += 64) {
        for (int ca = wave; ca < 16; ca += 4)
            gl_lds16(A + (size_t)(m0 + ca * 8 + lrow8) * K + k0 + lcolS, &As[ca * 512]);
        for (int cb = wave; cb < 8; cb += 4)
            gl_lds16(Wt + (size_t)(n0 + cb * 8 + lrow8) * K + k0 + lcolS, &Bs[cb * 512]);
        __syncthreads();
        #pragma unroll
        for (int s = 0; s < 2; s++) {
            const int co = (((s * 4 + quad) ^ fr7) << 3);
            short8 af[4], bfv[2];
            #pragma unroll
            for (int i = 0; i < 4; i++) af[i] = *(const short8*)&As[(wm + i * 16 + fr) * 64 + co];
            #pragma unroll
            for (int j = 0; j < 2; j++) bfv[j] = *(const short8*)&Bs[(wn + j * 16 + fr) * 64 + co];
            #pragma unroll
            for (int i = 0; i < 4; i++)
                #pragma unroll
                for (int j = 0; j < 2; j++)
                    acc[i][j] = __builtin_amdgcn_mfma_f32_16x16x32_bf16(af[i], bfv[j], acc[i][j], 0, 0, 0);
        }
        __syncthreads();
    }

    if (EPI == 0) {
        #pragma unroll
        for (int j = 0; j < 2; j++) {
            int n = n0 + wn + j * 16 + fr;
            float bv = b1[n];
            #pragma unroll
            for (int i = 0; i < 4; i++) {
                int mb = m0 + wm + i * 16 + quad * 4;
                #pragma unroll
                for (int r = 0; r < 4; r++)
                    o1[(size_t)(mb + r) * Ncols + n] = f2b(acc[i][j][r] + bv);
            }
        }
    } else if (EPI == 1) {
        float bv[2];
        #pragma unroll
        for (int j = 0; j < 2; j++) {
            int nn = n0 + wn + j * 16 + fr;
            int c = nn >> 1;
            bv[j] = (fr & 1) ? b2[c] : b1[c];
        }
        #pragma unroll
        for (int i = 0; i < 4; i++) {
            #pragma unroll
            for (int r = 0; r < 4; r++) {
                float s = 0.f;
                #pragma unroll
                for (int j = 0; j < 2; j++) {
                    float v = acc[i][j][r] + bv[j];
                    s += v * __shfl_xor(v, 1);
                }
                s += __shfl_xor(s, 2);
                s += __shfl_xor(s, 4);
                s += __shfl_xor(s, 8);
                if (fr == 0)
                    atomicAdd(&CBout[m0 + wm + i * 16 + quad * 4 + r], s * 0.5f);
            }
        }
    } else if (EPI == 2) {
        #pragma unroll
        for (int i = 0; i < 4; i++) {
            int mb = m0 + wm + i * 16 + quad * 4;
            float cbr[4];
            #pragma unroll
            for (int r = 0; r < 4; r++) cbr[r] = CBin[mb + r];
            #pragma unroll
            for (int j = 0; j < 2; j++) {
                int n = n0 + wn + j * 16 + fr;
                float bv = b1[n];
                #pragma unroll
                for (int r = 0; r < 4; r++) {
                    size_t off = (size_t)(mb + r) * 512 + n;
                    float delta = softplus_f(acc[i][j][r] + bv);
                    float xssm = delta * b2f(A[off]) * cbr[r];
                    o1[off] = f2b(silu_f(xssm) * b2f(Xres[off]));
                }
            }
        }
    } else {  // EPI 3: proj + de-norm + transpose, fp32 out
        #pragma unroll
        for (int j = 0; j < 2; j++) {
            int t = n0 + wn + j * 16 + fr;
            float bv = b1[t];
            #pragma unroll
            for (int i = 0; i < 4; i++) {
                int mb = m0 + wm + i * 16 + quad * 4;
                int b = mb >> 9;
                int nv = mb & 511;
                if (nv < CN) {
                    floatx4 o;
                    #pragma unroll
                    for (int r = 0; r < 4; r++) {
                        int sn = b * CN + nv + r;
                        o[r] = (acc[i][j][r] + bv) * stdev[sn] + means[sn];
                    }
                    *(floatx4*)(outf + ((size_t)(b * CT + t)) * CN + nv) = o;
                }
            }
        }
    }
}

// ---- conv as implicit MFMA GEMM, 64x64 tile (33KB LDS, 4 blocks/CU), grid 2048.
// Zeroes CBv at entry. ----
__global__ __launch_bounds__(256) void conv_mfma_kernel(const bf16* __restrict__ Wc,
                                                        const bf16* __restrict__ xpT,
                                                        const float* __restrict__ bias,
                                                        bf16* __restrict__ Out,
                                                        float* __restrict__ CBvZ) {
    __shared__ __align__(16) short As[3 * 64 * 64];
    __shared__ __align__(16) short Bs[72 * 64];
    const int tid = threadIdx.x;
    const int lane = tid & 63;
    const int wave = tid >> 6;
    int bx = blockIdx.x;
    if (bx < 128 && tid < 128) CBvZ[bx * 128 + tid] = 0.0f;
    int b = bx >> 6, rem = bx & 63;
    int mt = rem >> 3, nt = rem & 7;
    const int m0 = mt * 64, n0 = nt * 64;
    const bf16* xb = xpT + (size_t)b * PADL * 512;

    const int lrow8 = lane >> 3;
    const int lcolS = (((lane & 7) ^ lrow8) << 3);
    const int wm = (wave & 1) * 32, wn = (wave >> 1) * 32;
    const int fr = lane & 15, quad = lane >> 4;
    const int fr7 = fr & 7;

    floatx4 acc[2][2];
    #pragma unroll
    for (int i = 0; i < 2; i++)
        #pragma unroll
        for (int j = 0; j < 2; j++) acc[i][j] = (floatx4){0.f, 0.f, 0.f, 0.f};

    for (int k0 = 0; k0 < 512; k0 += 64) {
        // A: 3 taps x 64 rows = 24 chunks of 8 rows
        for (int ga = wave; ga < 24; ga += 4) {
            int tap = ga >> 3, rg = ga & 7;
            gl_lds16(Wc + (size_t)tap * 262144 + (size_t)(m0 + rg * 8 + lrow8) * 512 + k0 + lcolS,
                     &As[tap * 4096 + rg * 512]);
        }
        // B: 72 rows = 9 chunks of 8 rows (66 needed; over-read stays in slab)
        for (int gb = wave; gb < 9; gb += 4) {
            gl_lds16(xb + (size_t)(n0 + gb * 8 + lrow8) * 512 + k0 + lcolS, &Bs[gb * 512]);
        }
        __syncthreads();
        #pragma unroll
        for (int s = 0; s < 2; s++) {
            const int sq = s * 4 + quad;
            #pragma unroll
            for (int tap = 0; tap < 3; tap++) {
                const int coA = ((sq ^ fr7) << 3);
                const int coB = ((sq ^ ((fr + tap) & 7)) << 3);
                short8 af[2], bfv[2];
                #pragma unroll
                for (int i = 0; i < 2; i++)
                    af[i] = *(const short8*)&As[tap * 4096 + (wm + i * 16 + fr) * 64 + coA];
                #pragma unroll
                for (int j = 0; j < 2; j++)
                    bfv[j] = *(const short8*)&Bs[(wn + j * 16 + fr + tap) * 64 + coB];
                #pragma unroll
                for (int i = 0; i < 2; i++)
                    #pragma unroll
                    for (int j = 0; j < 2; j++)
                        acc[i][j] = __builtin_amdgcn_mfma_f32_16x16x32_bf16(af[i], bfv[j], acc[i][j], 0, 0, 0);
            }
        }
        __syncthreads();
    }
    bf16* ob = Out + (size_t)b * CF * CT2;
    #pragma unroll
    for (int i = 0; i < 2; i++) {
        int mb = m0 + wm + i * 16 + quad * 4;
        #pragma unroll
        for (int r = 0; r < 4; r++) {
            float bv = bias[mb + r];
            #pragma unroll
            for (int j = 0; j < 2; j++) {
                int n = n0 + wn + j * 16 + fr;
                ob[(size_t)(mb + r) * CT2 + n] = f2b(silu_f(acc[i][j][r] + bv));
            }
        }
    }
}

// ---- out-GEMM (K=512, N=256) + rms scale computation. M-tile 32, grid 512. ----
__global__ __launch_bounds__(256) void gemm_scl_kernel(const bf16* __restrict__ A,
                                                       const bf16* __restrict__ Wt,
                                                       const float* __restrict__ bias,
                                                       bf16* __restrict__ Xo,
                                                       float* __restrict__ SCL) {
    __shared__ __align__(16) short As[32 * 64];
    __shared__ __align__(16) short Bs[256 * 64];
    __shared__ float red[4][32];
    const int tid = threadIdx.x;
    const int lane = tid & 63;
    const int wave = tid >> 6;
    const int m0 = blockIdx.x * 32;

    const int lrow8 = lane >> 3;
    const int lcolS = (((lane & 7) ^ lrow8) << 3);
    const int wn = wave * 64;
    const int fr = lane & 15, quad = lane >> 4;
    const int fr7 = fr & 7;

    floatx4 acc[2][4];
    #pragma unroll
    for (int i = 0; i < 2; i++)
        #pragma unroll
        for (int j = 0; j < 4; j++) acc[i][j] = (floatx4){0.f, 0.f, 0.f, 0.f};

    for (int k0 = 0; k0 < 512; k0 += 64) {
        for (int c = wave; c < 4; c += 4)
            gl_lds16(A + (size_t)(m0 + c * 8 + lrow8) * 512 + k0 + lcolS, &As[c * 512]);
        for (int c = wave; c < 32; c += 4)
            gl_lds16(Wt + (size_t)(c * 8 + lrow8) * 512 + k0 + lcolS, &Bs[c * 512]);
        __syncthreads();
        #pragma unroll
        for (int s = 0; s < 2; s++) {
            const int co = (((s * 4 + quad) ^ fr7) << 3);
            short8 af[2], bfv[4];
            #pragma unroll
            for (int i = 0; i < 2; i++) af[i] = *(const short8*)&As[(i * 16 + fr) * 64 + co];
            #pragma unroll
            for (int j = 0; j < 4; j++) bfv[j] = *(const short8*)&Bs[(wn + j * 16 + fr) * 64 + co];
            #pragma unroll
            for (int i = 0; i < 2; i++)
                #pragma unroll
                for (int j = 0; j < 4; j++)
                    acc[i][j] = __builtin_amdgcn_mfma_f32_16x16x32_bf16(af[i], bfv[j], acc[i][j], 0, 0, 0);
        }
        __syncthreads();
    }
    #pragma unroll
    for (int j = 0; j < 4; j++) {
        float bv = bias[wn + j * 16 + fr];
        #pragma unroll
        for (int i = 0; i < 2; i++)
            #pragma unroll
            for (int r = 0; r < 4; r++) acc[i][j][r] += bv;
    }
    #pragma unroll
    for (int i = 0; i < 2; i++) {
        #pragma unroll
        for (int r = 0; r < 4; r++) {
            float s = 0.f;
            #pragma unroll
            for (int j = 0; j < 4; j++) s += acc[i][j][r] * acc[i][j][r];
            #pragma unroll
            for (int o = 8; o > 0; o >>= 1) s += __shfl_xor(s, o);
            if (fr == 0) red[wave][i * 16 + quad * 4 + r] = s;
        }
    }
    __syncthreads();
    if (tid < 32) {
        float tot = red[0][tid] + red[1][tid] + red[2][tid] + red[3][tid];
        SCL[m0 + tid] = rsqrtf(tot * (1.0f / CT) + 1e-5f);
    }
    #pragma unroll
    for (int j = 0; j < 4; j++) {
        int n = wn + j * 16 + fr;
        #pragma unroll
        for (int i = 0; i < 2; i++) {
            int rl = i * 16 + quad * 4;
            #pragma unroll
            for (int r = 0; r < 4; r++)
                Xo[(size_t)(m0 + rl + r) * CT + n] = f2b(acc[i][j][r]);
        }
    }
}

extern "C" void kernel_launch(void* const* d_in, const int* in_sizes, int n_in,
                              void* d_out, int out_size, void* d_ws, size_t ws_size,
                              hipStream_t stream) {
    const float* x_enc  = (const float*)d_in[0];
    const float* x_mark = (const float*)d_in[1];
    const float* norm_w = (const float*)d_in[4];
    const float* inp_W  = (const float*)d_in[5];
    const float* inp_b  = (const float*)d_in[6];
    const float* conv_W = (const float*)d_in[7];
    const float* conv_b = (const float*)d_in[8];
    const float* convlin_W = (const float*)d_in[9];
    const float* convlin_b = (const float*)d_in[10];
    const float* fc1_W = (const float*)d_in[11];
    const float* fc1_b = (const float*)d_in[12];
    const float* fc2_W = (const float*)d_in[13];
    const float* fc2_b = (const float*)d_in[14];
    const float* fc3_W = (const float*)d_in[15];
    const float* fc3_b = (const float*)d_in[16];
    const float* D_W   = (const float*)d_in[17];
    const float* D_b   = (const float*)d_in[18];
    const float* out_W = (const float*)d_in[19];
    const float* out_b = (const float*)d_in[20];
    const float* proj_W = (const float*)d_in[21];
    const float* proj_b = (const float*)d_in[22];

    // ---- workspace layout ----
    char* ws = (char*)d_ws;
    float* MEANS = (float*)(ws);
    float* STDEV = (float*)(ws + 65536);
    float* CBv   = (float*)(ws + 131072);
    float* SCL   = (float*)(ws + 196608);    // 64 KB slot (16384 fp32)
    bf16* wt = (bf16*)(ws + 262144);
    bf16* wt_g1      = wt;                   // 3 x [1024][256]  (nw-folded inp^T | D^T)
    bf16* wt_g3      = wt + 786432;          // 3 x [fc1^T | fc2⊕fc3]
    bf16* wt_convlin = wt + 2359296;
    bf16* wt_out     = wt + 3145728;
    bf16* wt_proj    = wt + 3538944;
    bf16* wt_conv    = wt + 3604480;         // 3 x [3][512][512]
    bf16* xpT = (bf16*)(ws + 12189696);      // [32][528][512]
    const size_t POOLB = 16777216;
    bf16* pool[4] = {
        (bf16*)(ws + 29491200),
        (bf16*)(ws + 29491200 + POOLB),
        (bf16*)(ws + 29491200 + 2 * POOLB),
        (bf16*)(ws + 29491200 + 3 * POOLB),
    };
    float* out = (float*)d_out;

    // ---- single merged prepack (weights + conv + pads + CBv zero) ----
    P8 p;
    p.s[0] = inp_W;  p.d[0] = wt_g1;
    p.s[1] = D_W;    p.d[1] = wt_g1 + 131072;
    p.s[2] = fc1_W;  p.d[2] = wt_g3;
    p.s[3] = fc2_W;  p.d[3] = wt_g3 + 262144;
    p.s[4] = fc3_W;  p.d[4] = wt_g3 + 262144;
    p.s[5] = convlin_W; p.d[5] = wt_convlin;
    p.s[6] = out_W;  p.d[6] = wt_out;
    p.s[7] = proj_W; p.d[7] = wt_proj;
    int convBlocks = (CONVN + 32768 + MROWS + 255) / 256;
    prepack_all_kernel<<<MTILES + convBlocks, 256, 0, stream>>>(
        p, norm_w, conv_W, wt_conv, xpT, CBv);

    // ---- stats + build: raw x -> pool[0].lo, rms scale -> SCL ----
    buildx_kernel<<<256, 256, 0, stream>>>(x_enc, x_mark, MEANS, STDEV, pool[0], SCL);

    // 4-pool rotation
    int ia = 0, ico = 1, ires = 2, iout = 3;
    for (int i = 0; i < 3; i++) {
        bf16* A  = pool[ia];
        bf16* XCO = pool[ico];
        bf16* XRES = pool[ires];
        bf16* OUTP = pool[iout];

        // [xp|xres] = (x*scl) @ [nw∘inp | nw∘D] + b : xp -> xpT^T, xres -> XRES
        mgemm_kernel<1><<<dim3(128, 8), 256, 0, stream>>>(
            A, wt_g1 + (size_t)i * 262144, inp_b + i * CT2, D_b + i * CT2, SCL,
            xpT, XRES, 256, 1024);
        // xc = silu(conv(xp)) -> A ; zeroes CBv
        conv_mfma_kernel<<<2048, 256, 0, stream>>>(wt_conv + (size_t)i * 786432, xpT,
                                                   conv_b + i * CF, A, CBv);
        // xco = xc @ convlin + b -> XCO
        g64_kernel<0><<<dim3(128, 8), 256, 0, stream>>>(
            A, wt_convlin + (size_t)i * 262144, 512, convlin_b + i * CT2, nullptr,
            nullptr, nullptr, nullptr, XCO, 512, nullptr, nullptr, nullptr);
        // cb atomics
        g64_kernel<1><<<dim3(128, 8), 256, 0, stream>>>(
            XCO, wt_g3 + (size_t)i * 524288 + 262144, 512, fc2_b + i * CT, fc3_b + i * CT,
            nullptr, nullptr, CBv, nullptr, 0, nullptr, nullptr, nullptr);
        // g = gate(fc1, xco, cb, xres) -> A
        g64_kernel<2><<<dim3(128, 8), 256, 0, stream>>>(
            XCO, wt_g3 + (size_t)i * 524288, 512, fc1_b + i * CT2, nullptr,
            CBv, XRES, nullptr, A, 512, nullptr, nullptr, nullptr);
        // x_next = g @ out_W + b -> OUTP.lo ; scl -> SCL
        gemm_scl_kernel<<<512, 256, 0, stream>>>(
            A, wt_out + (size_t)i * 131072, out_b + i * CT, OUTP, SCL);

        int na = iout, nco = ia, nres = ico, nout = ires;
        ia = na; ico = nco; ires = nres; iout = nout;
    }

    // x_final in pool[ia].lo. dec = x @ proj_W + b, de-norm + transpose to out
    g64_kernel<3><<<dim3(128, 4), 256, 0, stream>>>(
        pool[ia], wt_proj, 256, proj_b, nullptr, nullptr, nullptr, nullptr,
        nullptr, 0, MEANS, STDEV, out);
}